// Round 6
// baseline (3407.482 us; speedup 1.0000x reference)
//
#include <hip/hip_runtime.h>
#include <cstdint>
#include <cstddef>

// ---------------------------------------------------------------------------
// PointNet++ (B=8, N=4096, K=64, N1=2048, N2=512, r1=0.2, r2=0.4), fp32.
// Selection stages (FPS argmax, ball-query top-k) use __f*_rn intrinsics in
// numpy's association order -> selected index sets match bit-exactly.
// R15: chunked-FPS overlap with stream-ordered dependencies ONLY (no
// cross-block sync; R14's cooperative streaming failed correctness).
//  - fps1 split into 4 chunks of 512 selections; fps2 into 2 chunks of 256.
//    Chunk state: sorted scp (float4 {x,y,z,key}) persisted once; per-thread
//    mind[] saved/reloaded per chunk. Per-thread candidate is exactly
//    max_j key(mind[j],oi[j]) (invariant), so recomputing at a chunk start
//    is bit-exact.
//  - Each stage launch = 8 fps-chunk blocks + 240 worker blocks running
//    fused bq+mlp for the PREVIOUS chunk's centers (read earlier-launch data
//    only). LDS 94720 B -> 1 block/CU, 248 blocks <= 256 CUs: workers never
//    share a CU with the serial fps blocks.
//  - nbr1/nbr2 global arrays eliminated (bq writes LDS, mlp consumes in-wave
//    -- same values as the R13 global-array path).
// R13: R9 combine (slots[3] + lane63 atomicMax + u64 DPP); float4-packed
// sorted coords+key so the dependent coord lookup is one ds_read_b128.
// R5 core: exact lazy pruning; Morton-bucket-sorted points; per-thread bbox
// lower bound skips the recompute when it cannot change any mind[j].
// Key = (d2bits<<24)|((~orig&0xFFF)<<12)|sortedpos.
// ---------------------------------------------------------------------------

static constexpr int Bc = 8;     // batch (clouds)
static constexpr int Np = 4096;  // points per cloud
static constexpr int Kn = 64;    // max neighbors
static constexpr int M1 = 2048;  // SA1 centers
static constexpr int M2 = 512;   // SA2 centers
static constexpr int LDX = 132;  // row stride of X = [x2 (128) | c2 (3) | pad]

#define DEVINL __device__ __forceinline__

// exact replication of np: ((dx*dx + dy*dy) + dz*dz), no fma contraction
DEVINL float d2_exact(float ax, float ay, float az, float bx, float by, float bz) {
    float dx = __fsub_rn(ax, bx);
    float dy = __fsub_rn(ay, by);
    float dz = __fsub_rn(az, bz);
    float xx = __fmul_rn(dx, dx);
    float yy = __fmul_rn(dy, dy);
    float zz = __fmul_rn(dz, dz);
    return __fadd_rn(__fadd_rn(xx, yy), zz);
}

template <int CTRL, int RM, int BM>
DEVINL unsigned long long dpp_max_step(unsigned long long k) {
    unsigned lo = (unsigned)k, hi = (unsigned)(k >> 32);
    unsigned slo = (unsigned)__builtin_amdgcn_update_dpp(0, (int)lo, CTRL, RM, BM, true);
    unsigned shi = (unsigned)__builtin_amdgcn_update_dpp(0, (int)hi, CTRL, RM, BM, true);
    unsigned long long s = ((unsigned long long)shi << 32) | (unsigned long long)slo;
    return s > k ? s : k;
}

DEVINL unsigned long long wave_max_u64_dpp(unsigned long long k) {
    k = dpp_max_step<0x111, 0xf, 0xf>(k);  // row_shr:1
    k = dpp_max_step<0x112, 0xf, 0xf>(k);  // row_shr:2
    k = dpp_max_step<0x114, 0xf, 0xf>(k);  // row_shr:4
    k = dpp_max_step<0x118, 0xf, 0xf>(k);  // row_shr:8
    k = dpp_max_step<0x142, 0xa, 0xf>(k);  // row_bcast:15
    k = dpp_max_step<0x143, 0xc, 0xf>(k);  // row_bcast:31 -> lane 63 = wave max
    return k;
}

DEVINL unsigned mort3(unsigned v) {  // 3 bits -> bits 0,3,6
    return (v & 1u) | ((v & 2u) << 2) | ((v & 4u) << 4);
}

DEVINL unsigned cell_of(float x, float y, float z) {
    int ix = (int)(x * 8.0f); ix = ix < 0 ? 0 : (ix > 7 ? 7 : ix);
    int iy = (int)(y * 8.0f); iy = iy < 0 ? 0 : (iy > 7 ? 7 : iy);
    int iz = (int)(z * 8.0f); iz = iz < 0 ? 0 : (iz > 7 ? 7 : iz);
    return mort3((unsigned)ix) | (mort3((unsigned)iy) << 1) | (mort3((unsigned)iz) << 2);
}

// inclusive Hillis-Steele scan over 512 entries, 512 threads. 9 barriers.
DEVINL unsigned* scan512(unsigned* h0, unsigned* h1, int t) {
    unsigned* src = h0; unsigned* dst = h1;
    for (int d = 1; d < 512; d <<= 1) {
        unsigned v = src[t];
        if (t >= d) v += src[t - d];
        dst[t] = v;
        __syncthreads();
        unsigned* tmp = src; src = dst; dst = tmp;
    }
    return src;
}

// ---------------------------------------------------------------------------
// FPS chunk: selections [s_begin, s_end) for one cloud. 512 threads.
// NPTS points, PT = NPTS/512 per thread. State in scp_g (sorted, persisted at
// chunk 0) and mind_g (per-thread min distances, saved every chunk).
// Journal (LDS) holds the chunk's selected coords for the caller to flush.
// ---------------------------------------------------------------------------
template <int NPTS, int PT>
DEVINL void fps_chunk_body(const float* __restrict__ srcpts,
                           float4* __restrict__ scp_g,
                           float* __restrict__ mind_g,
                           char* smem, int t, int lane,
                           int s_begin, int s_end) {
    constexpr int NT = NPTS / PT;   // 512
    float4* scp = (float4*)smem;
    unsigned* h0 = (unsigned*)(smem + 65536);
    unsigned* h1 = (unsigned*)(smem + 67584);
    unsigned long long* slots = (unsigned long long*)(smem + 69632);
    float* journal = (float*)(smem + 69664);

    float px[PT], py[PT], pz[PT], mind[PT];
    unsigned oi[PT];
    unsigned long long ck = 0;

    if (s_begin == 0) {
        // -------- chunk 0: load, Morton-bucket sort, persist, seed --------
        float gx[PT], gy[PT], gz[PT];
        unsigned gc[PT];
        #pragma unroll
        for (int j = 0; j < PT; ++j) {
            int p = j * NT + t;
            gx[j] = srcpts[p * 3 + 0];
            gy[j] = srcpts[p * 3 + 1];
            gz[j] = srcpts[p * 3 + 2];
            gc[j] = cell_of(gx[j], gy[j], gz[j]);
        }
        float x0 = srcpts[0], y0 = srcpts[1], z0 = srcpts[2];
        h0[t] = 0;
        if (t == 0) { slots[0] = 0; slots[1] = 0; slots[2] = 0; }
        __syncthreads();
        #pragma unroll
        for (int j = 0; j < PT; ++j) atomicAdd(&h0[gc[j]], 1u);
        __syncthreads();
        unsigned cnt = h0[t];
        unsigned* inc = scan512(h0, h1, t);
        inc[t] -= cnt;
        __syncthreads();
        #pragma unroll
        for (int j = 0; j < PT; ++j) {
            unsigned p = atomicAdd(&inc[gc[j]], 1u);
            unsigned key = ((0xFFFu - (unsigned)(j * NT + t)) << 12) | p;
            scp[p] = make_float4(gx[j], gy[j], gz[j], __uint_as_float(key));
        }
        __syncthreads();
        for (int k = t; k < NPTS; k += NT) scp_g[k] = scp[k];  // persist sort
        #pragma unroll
        for (int j = 0; j < PT; ++j) {
            float4 v = scp[t * PT + j];
            px[j] = v.x; py[j] = v.y; pz[j] = v.z;
            oi[j] = __float_as_uint(v.w);
        }
        #pragma unroll
        for (int j = 0; j < PT; ++j) {
            float d = d2_exact(px[j], py[j], pz[j], x0, y0, z0);
            mind[j] = d;
            unsigned long long kj =
                ((unsigned long long)__float_as_uint(d) << 24) | (unsigned long long)oi[j];
            if (kj > ck) ck = kj;
        }
        if (t == 0) { journal[0] = x0; journal[1] = y0; journal[2] = z0; }
    } else {
        // -------- chunk >0: restore state (bit-exact recompute of ck) -----
        if (t == 0) { slots[0] = 0; slots[1] = 0; slots[2] = 0; }
        for (int k = t; k < NPTS; k += NT) scp[k] = scp_g[k];
        __syncthreads();
        #pragma unroll
        for (int j = 0; j < PT; ++j) {
            float4 v = scp[t * PT + j];
            px[j] = v.x; py[j] = v.y; pz[j] = v.z;
            oi[j] = __float_as_uint(v.w);
        }
        #pragma unroll
        for (int j = 0; j < PT; ++j) mind[j] = mind_g[t * PT + j];
        #pragma unroll
        for (int j = 0; j < PT; ++j) {
            unsigned long long kj =
                ((unsigned long long)__float_as_uint(mind[j]) << 24) |
                (unsigned long long)oi[j];
            if (kj > ck) ck = kj;
        }
    }

    float lox = px[0], hix = px[0], loy = py[0], hiy = py[0], loz = pz[0], hiz = pz[0];
    #pragma unroll
    for (int j = 1; j < PT; ++j) {
        lox = fminf(lox, px[j]); hix = fmaxf(hix, px[j]);
        loy = fminf(loy, py[j]); hiy = fmaxf(hiy, py[j]);
        loz = fminf(loz, pz[j]); hiz = fmaxf(hiz, pz[j]);
    }

    float bmax = __uint_as_float((unsigned)(ck >> 24));
    unsigned long long wkey = wave_max_u64_dpp(ck);
    if (lane == 63) atomicMax(&slots[1], wkey);

    int rd = 1, wr = 2, rs = 0;
    for (int s = (s_begin == 0 ? 1 : s_begin); s < s_end; ++s) {
        __syncthreads();
        unsigned long long km = slots[rd];
        if (t == 0) slots[rs] = 0;
        unsigned spos = (unsigned)km & 0xFFFu;
        float4 cc = scp[spos];
        float cx = cc.x, cy = cc.y, cz = cc.z;
        if (t == 0) {
            int jj = (s - s_begin) * 3;
            journal[jj + 0] = cx; journal[jj + 1] = cy; journal[jj + 2] = cz;
        }
        float dxv = fmaxf(fmaxf(lox - cx, cx - hix), 0.0f);
        float dyv = fmaxf(fmaxf(loy - cy, cy - hiy), 0.0f);
        float dzv = fmaxf(fmaxf(loz - cz, cz - hiz), 0.0f);
        float L = dxv * dxv + dyv * dyv + dzv * dzv;
        bool fire = (L * 0.999f <= bmax);
        if (fire) {
            unsigned long long nck = 0;
            #pragma unroll
            for (int j = 0; j < PT; ++j) {
                float d = d2_exact(px[j], py[j], pz[j], cx, cy, cz);
                float m = fminf(mind[j], d);
                mind[j] = m;
                unsigned long long kj =
                    ((unsigned long long)__float_as_uint(m) << 24) | (unsigned long long)oi[j];
                if (kj > nck) nck = kj;
            }
            ck = nck;
            bmax = __uint_as_float((unsigned)(ck >> 24));
        }
        if (__ballot(fire) != 0ull) wkey = wave_max_u64_dpp(ck);
        if (lane == 63) atomicMax(&slots[wr], wkey);
        int nrd = wr; wr = rs; rs = rd; rd = nrd;
    }
    __syncthreads();   // journal complete; mind final
    #pragma unroll
    for (int j = 0; j < PT; ++j) mind_g[t * PT + j] = mind[j];
}

// ---------------------------------------------------------------------------
// Ball-query core: one wave, one center. d2 per lane in registers; >K in
// radius -> compact to LDS buf + exact kth-smallest binary search. Ties by
// smallest index (== lax.top_k). out is LDS; slots 0..63 filled, -1 pad.
// ---------------------------------------------------------------------------
template <int NPT>
DEVINL void bq_core(const float* __restrict__ pb, float cx, float cy, float cz,
                    float r2, int* out, uint2* buf, int lane) {
    constexpr int CH = NPT / 64;
    constexpr int CAP = 1024;
    const unsigned r2b = __float_as_uint(r2);

    unsigned ub[CH];
    int cnt = 0;
    #pragma unroll
    for (int j = 0; j < CH; ++j) {
        int p = j * 64 + lane;
        float d = d2_exact(pb[p * 3 + 0], pb[p * 3 + 1], pb[p * 3 + 2], cx, cy, cz);
        ub[j] = __float_as_uint(d);   // d >= 0 -> bits monotonic
        cnt += __popcll(__ballot(ub[j] <= r2b));
    }
    const unsigned long long lml = (1ull << lane) - 1ull;

    if (cnt <= Kn) {
        int basep = 0;
        #pragma unroll
        for (int j = 0; j < CH; ++j) {
            bool v = ub[j] <= r2b;
            unsigned long long mk = __ballot(v);
            if (v) out[basep + __popcll(mk & lml)] = j * 64 + lane;
            basep += __popcll(mk);
        }
        if (lane >= cnt) out[lane] = -1;
    } else if (cnt <= CAP) {
        int basep = 0;
        #pragma unroll
        for (int j = 0; j < CH; ++j) {
            bool v = ub[j] <= r2b;
            unsigned long long mk = __ballot(v);
            if (v) buf[basep + __popcll(mk & lml)] =
                       make_uint2(ub[j], (unsigned)(j * 64 + lane));
            basep += __popcll(mk);
        }
        const int C2 = (cnt + 63) >> 6;   // wave-uniform
        unsigned cb[CAP / 64], ci[CAP / 64];
        #pragma unroll
        for (int e = 0; e < CAP / 64; ++e) {
            if (e >= C2) break;
            int p = e * 64 + lane;
            uint2 v = buf[p];
            cb[e] = (p < cnt) ? v.x : 0xFFFFFFFFu;
            ci[e] = v.y;
        }
        unsigned lo = 0, hi = r2b;
        while (lo < hi) {
            unsigned mid = lo + ((hi - lo) >> 1);
            int c = 0;
            #pragma unroll
            for (int e = 0; e < CAP / 64; ++e) {
                if (e >= C2) break;
                c += __popcll(__ballot(cb[e] <= mid));
            }
            if (c >= Kn) hi = mid; else lo = mid + 1;
        }
        const unsigned tt = lo;
        int cntLess = 0;
        #pragma unroll
        for (int e = 0; e < CAP / 64; ++e) {
            if (e >= C2) break;
            cntLess += __popcll(__ballot(cb[e] < tt));
        }
        const int quota = Kn - cntLess;
        int baseLt = 0, eqseen = 0;
        #pragma unroll
        for (int e = 0; e < CAP / 64; ++e) {
            if (e >= C2) break;
            bool lt = cb[e] < tt;
            bool eq = cb[e] == tt;
            unsigned long long mlt = __ballot(lt);
            unsigned long long meq = __ballot(eq);
            if (lt) out[baseLt + __popcll(mlt & lml)] = (int)ci[e];
            if (eq) {
                int rr = eqseen + __popcll(meq & lml);
                if (rr < quota) out[cntLess + rr] = (int)ci[e];
            }
            baseLt += __popcll(mlt);
            eqseen += __popcll(meq);
        }
    } else {
        unsigned lo = 0, hi = r2b;
        while (lo < hi) {
            unsigned mid = lo + ((hi - lo) >> 1);
            int c = 0;
            #pragma unroll
            for (int j = 0; j < CH; ++j) c += __popcll(__ballot(ub[j] <= mid));
            if (c >= Kn) hi = mid; else lo = mid + 1;
        }
        const unsigned tt = lo;
        int cntLess = 0;
        #pragma unroll
        for (int j = 0; j < CH; ++j) cntLess += __popcll(__ballot(ub[j] < tt));
        const int quota = Kn - cntLess;
        int baseLt = 0, eqseen = 0;
        #pragma unroll
        for (int j = 0; j < CH; ++j) {
            bool lt = ub[j] < tt;
            bool eq = ub[j] == tt;
            unsigned long long mlt = __ballot(lt);
            unsigned long long meq = __ballot(eq);
            if (lt) out[baseLt + __popcll(mlt & lml)] = j * 64 + lane;
            if (eq) {
                int rr = eqseen + __popcll(meq & lml);
                if (rr < quota) out[cntLess + rr] = j * 64 + lane;
            }
            baseLt += __popcll(mlt);
            eqseen += __popcll(meq);
        }
    }
}

// ---------------------------------------------------------------------------
// MLP1 core (wave, one center): 3 -> 64 relu -> 64 relu, masked max.
// ---------------------------------------------------------------------------
DEVINL void mlp1_core(const float* __restrict__ pb, float cx, float cy, float cz,
                      const int* nbrL, const float* __restrict__ w1aT,
                      const float* __restrict__ w1bT, const float* __restrict__ b1b,
                      float* __restrict__ orow, int lane) {
    const int ii = nbrL[lane];
    const bool valid = ii >= 0;
    const int i2 = valid ? ii : 0;
    const float* pp = pb + (size_t)i2 * 3;
    float rx = pp[0] - cx, ry = pp[1] - cy, rz = pp[2] - cz;
    float h1[64];
    #pragma unroll
    for (int h = 0; h < 64; ++h) {
        float4 wv = ((const float4*)w1aT)[h];
        float a = fmaf(rx, wv.x, fmaf(ry, wv.y, fmaf(rz, wv.z, wv.w)));
        h1[h] = fmaxf(a, 0.0f);
    }
    for (int c4 = 0; c4 < 16; ++c4) {
        float v4[4];
        #pragma unroll
        for (int cq = 0; cq < 4; ++cq) {
            int c = c4 * 4 + cq;
            float acc = b1b[c];
            const float4* wr = (const float4*)(w1bT + (size_t)c * 64);
            #pragma unroll
            for (int q = 0; q < 16; ++q) {
                float4 wv = wr[q];
                acc = fmaf(h1[4 * q + 0], wv.x, acc);
                acc = fmaf(h1[4 * q + 1], wv.y, acc);
                acc = fmaf(h1[4 * q + 2], wv.z, acc);
                acc = fmaf(h1[4 * q + 3], wv.w, acc);
            }
            float v = fmaxf(acc, 0.0f);
            v = valid ? v : -__builtin_inff();
            #pragma unroll
            for (int o = 32; o > 0; o >>= 1) v = fmaxf(v, __shfl_xor(v, o, 64));
            v4[cq] = v;
        }
        if (lane == 0)
            ((float4*)orow)[c4] = make_float4(v4[0], v4[1], v4[2], v4[3]);
    }
}

// ---------------------------------------------------------------------------
// MLP2 core (wave, one center): [x1(64)|relpos(3)] -> 128 relu -> 128 relu,
// masked max; writes X row cols 0..127.
// ---------------------------------------------------------------------------
DEVINL void mlp2_core(const float* __restrict__ x1b, const float* __restrict__ c1b,
                      float cx, float cy, float cz, const int* nbrL,
                      const float* __restrict__ w2aT, const float* __restrict__ w2bT,
                      const float* __restrict__ b2b, float* __restrict__ orow,
                      int lane) {
    const int ii = nbrL[lane];
    const bool valid = ii >= 0;
    const int i2 = valid ? ii : 0;

    float x[68];
    const float4* xr = (const float4*)(x1b + (size_t)i2 * 64);
    #pragma unroll
    for (int q = 0; q < 16; ++q) {
        float4 v = xr[q];
        x[4 * q + 0] = v.x; x[4 * q + 1] = v.y;
        x[4 * q + 2] = v.z; x[4 * q + 3] = v.w;
    }
    const float* cp = c1b + (size_t)i2 * 3;
    x[64] = cp[0] - cx;
    x[65] = cp[1] - cy;
    x[66] = cp[2] - cz;
    x[67] = 0.0f;

    float h1[128];
    #pragma unroll
    for (int h = 0; h < 128; ++h) {
        const float4* r4 = (const float4*)(w2aT + (size_t)h * 80);
        float acc = 0.0f;
        #pragma unroll
        for (int q = 0; q < 16; ++q) {
            float4 wv = r4[q];
            acc = fmaf(x[4 * q + 0], wv.x, acc);
            acc = fmaf(x[4 * q + 1], wv.y, acc);
            acc = fmaf(x[4 * q + 2], wv.z, acc);
            acc = fmaf(x[4 * q + 3], wv.w, acc);
        }
        float4 tl = r4[16];   // w64, w65, w66, bias
        acc = fmaf(x[64], tl.x, acc);
        acc = fmaf(x[65], tl.y, acc);
        acc = fmaf(x[66], tl.z, acc);
        acc += tl.w;
        h1[h] = fmaxf(acc, 0.0f);
    }
    for (int c4 = 0; c4 < 32; ++c4) {
        float v4[4];
        #pragma unroll
        for (int cq = 0; cq < 4; ++cq) {
            int c = c4 * 4 + cq;
            float acc = b2b[c];
            const float4* wr = (const float4*)(w2bT + (size_t)c * 128);
            #pragma unroll
            for (int q = 0; q < 32; ++q) {
                float4 wv = wr[q];
                acc = fmaf(h1[4 * q + 0], wv.x, acc);
                acc = fmaf(h1[4 * q + 1], wv.y, acc);
                acc = fmaf(h1[4 * q + 2], wv.z, acc);
                acc = fmaf(h1[4 * q + 3], wv.w, acc);
            }
            float v = fmaxf(acc, 0.0f);
            v = valid ? v : -__builtin_inff();
            #pragma unroll
            for (int o = 32; o > 0; o >>= 1) v = fmaxf(v, __shfl_xor(v, o, 64));
            v4[cq] = v;
        }
        if (lane == 0) {
            orow[c4 * 4 + 0] = v4[0]; orow[c4 * 4 + 1] = v4[1];
            orow[c4 * 4 + 2] = v4[2]; orow[c4 * 4 + 3] = v4[3];
        }
    }
}

// ---------------------------------------------------------------------------
// stage_kernel: 512 threads, LDS 94720 (1 block/CU).
//  fps_stage: 1 = fps1 chunk (blocks 0..7), 2 = fps2 chunk, 0 = none.
//  w_stage:   1 = weight prep, 2 = workers1 (bq1+mlp1), 3 = workers2
//             (bq2+mlp2), 0 = none. Worker blocks follow the fps blocks.
//  Workers handle centers [w_begin, w_begin + (1<<wsh)) for all 8 clouds.
//  All inter-role dependencies are across LAUNCHES (stream-ordered).
// ---------------------------------------------------------------------------
__global__ __launch_bounds__(512)
void stage_kernel(int fps_stage, int s_begin, int s_end,
                  int w_stage, int w_begin, int wsh,
                  const float* __restrict__ pos, float* __restrict__ c1,
                  float* __restrict__ c2, float* __restrict__ X,
                  float* __restrict__ x1,
                  float4* __restrict__ scp1_g, float* __restrict__ mind1_g,
                  float4* __restrict__ scp2_g, float* __restrict__ mind2_g,
                  const float* __restrict__ w1a, const float* __restrict__ b1a,
                  const float* __restrict__ w1b, const float* __restrict__ w2a,
                  const float* __restrict__ b2a, const float* __restrict__ w2b,
                  float* __restrict__ w1aT, float* __restrict__ w1bT,
                  float* __restrict__ w2aT, float* __restrict__ w2bT,
                  const float* __restrict__ b1b, const float* __restrict__ b2b) {
    __shared__ __align__(16) char smem[94720];
    const int t = threadIdx.x;
    const int lane = t & 63;
    const int wid = t >> 6;

    if (fps_stage > 0 && blockIdx.x < Bc) {
        const int b = blockIdx.x;
        float* journal = (float*)(smem + 69664);
        if (fps_stage == 1) {
            fps_chunk_body<Np, 8>(pos + (size_t)b * Np * 3, scp1_g + (size_t)b * Np,
                                  mind1_g + (size_t)b * Np, smem, t, lane,
                                  s_begin, s_end);
            int n = (s_end - s_begin) * 3;
            for (int i = t; i < n; i += 512)
                c1[(size_t)b * M1 * 3 + s_begin * 3 + i] = journal[i];
        } else {
            fps_chunk_body<M1, 4>(c1 + (size_t)b * M1 * 3, scp2_g + (size_t)b * M1,
                                  mind2_g + (size_t)b * M1, smem, t, lane,
                                  s_begin, s_end);
            int n = (s_end - s_begin) * 3;
            for (int i = t; i < n; i += 512)
                c2[(size_t)b * M2 * 3 + s_begin * 3 + i] = journal[i];
            for (int i = t; i < n; i += 512) {
                int s = i / 3, k = i - s * 3;
                X[(size_t)(b * M2 + s_begin + s) * LDX + 128 + k] = journal[i];
            }
        }
        return;
    }

    const int wb = (fps_stage > 0) ? (int)blockIdx.x - Bc : (int)blockIdx.x;
    const int nw = (fps_stage > 0) ? (int)gridDim.x - Bc : (int)gridDim.x;

    if (w_stage == 1) {
        // ---------------- weight-transpose prep ----------------
        int i = wb * 512 + t;  // 0..16383
        if (i < 64 * 4) {
            int h = i >> 2, d = i & 3;
            w1aT[i] = (d < 3) ? w1a[d * 64 + h] : b1a[h];
        }
        if (i < 64 * 64) {
            int c = i >> 6, h = i & 63;
            w1bT[i] = w1b[h * 64 + c];
        }
        if (i < 128 * 80) {
            int h = i / 80, d = i - h * 80;
            w2aT[i] = (d < 67) ? w2a[d * 128 + h] : ((d == 67) ? b2a[h] : 0.0f);
        }
        if (i < 128 * 128) {
            int c = i >> 7, h = i & 127;
            w2bT[i] = w2b[h * 128 + c];
        }
        return;
    }

    if (w_stage == 2) {
        // ---------------- workers1: fused bq1 + mlp1 ----------------
        uint2* cbuf = (uint2*)smem + (size_t)wid * 1024;       // 8 KB/wave
        int* nbrL = (int*)(smem + 65536) + wid * 64;
        const int span_mask = (1 << wsh) - 1;
        const int ntasks = Bc << wsh;
        for (int task = wb * 8 + wid; task < ntasks; task += nw * 8) {
            const int b = task >> wsh;
            const int s = w_begin + (task & span_mask);
            const int w = b * M1 + s;
            const float* cr = c1 + (size_t)w * 3;
            float cx = cr[0], cy = cr[1], cz = cr[2];
            const float* pb = pos + (size_t)b * Np * 3;
            bq_core<Np>(pb, cx, cy, cz, (float)(0.2 * 0.2), nbrL, cbuf, lane);
            mlp1_core(pb, cx, cy, cz, nbrL, w1aT, w1bT, b1b,
                      x1 + (size_t)w * 64, lane);
        }
        return;
    }

    if (w_stage == 3) {
        // ---------------- workers2: fused bq2 + mlp2 ----------------
        uint2* cbuf = (uint2*)smem + (size_t)wid * 1024;
        int* nbrL = (int*)(smem + 65536) + wid * 64;
        const int span_mask = (1 << wsh) - 1;
        const int ntasks = Bc << wsh;
        for (int task = wb * 8 + wid; task < ntasks; task += nw * 8) {
            const int b = task >> wsh;
            const int s = w_begin + (task & span_mask);
            const int w = b * M2 + s;
            const float* cr = c2 + (size_t)w * 3;
            float cx = cr[0], cy = cr[1], cz = cr[2];
            const float* c1b = c1 + (size_t)b * M1 * 3;
            bq_core<M1>(c1b, cx, cy, cz, (float)(0.4 * 0.4), nbrL, cbuf, lane);
            mlp2_core(x1 + (size_t)b * M1 * 64, c1b, cx, cy, cz, nbrL,
                      w2aT, w2bT, b2b, X + (size_t)w * LDX, lane);
        }
        return;
    }
}

// ---------------------------------------------------------------------------
// GEMM1: H[r][c] = relu(b3a[c] + sum_i X[r][i] * w3a[i][c]), K=131.
// ---------------------------------------------------------------------------
__global__ __launch_bounds__(256)
void gemm1_kernel(const float* __restrict__ X, const float* __restrict__ w3a,
                  const float* __restrict__ b3a, float* __restrict__ H) {
    const int r = blockIdx.x;
    const int c = threadIdx.x;
    const float* xr = X + (size_t)r * LDX;
    float acc = b3a[c];
    for (int i = 0; i < 131; ++i)
        acc = fmaf(xr[i], w3a[(size_t)i * 256 + c], acc);
    H[(size_t)r * 256 + c] = fmaxf(acc, 0.0f);
}

// ---------------------------------------------------------------------------
// GEMM2 fused with per-tile row max: 32x64 tile, BK=32.
// ---------------------------------------------------------------------------
__global__ __launch_bounds__(256)
void gemm2_kernel(const float* __restrict__ H, const float* __restrict__ w3b,
                  float* __restrict__ part) {
    __shared__ float As[32][33];
    __shared__ float Bs[32][64];
    __shared__ float red[8][64];
    const int bidx = blockIdx.x;
    const int nt = bidx & 15;
    const int mt = (bidx >> 4) & 15;
    const int b = bidx >> 8;
    const int row0 = b * M2 + mt * 32;
    const int col0 = nt * 64;
    const int t = threadIdx.x;
    const int rg = t >> 5, cg = t & 31;

    float acc[4][2] = {{0.f, 0.f}, {0.f, 0.f}, {0.f, 0.f}, {0.f, 0.f}};
    for (int k0 = 0; k0 < 256; k0 += 32) {
        #pragma unroll
        for (int q = 0; q < 4; ++q) {
            int id = t + q * 256;
            As[id >> 5][id & 31] = H[(size_t)(row0 + (id >> 5)) * 256 + k0 + (id & 31)];
        }
        #pragma unroll
        for (int q = 0; q < 8; ++q) {
            int id = t + q * 256;
            Bs[id >> 6][id & 63] = w3b[(size_t)(k0 + (id >> 6)) * 1024 + col0 + (id & 63)];
        }
        __syncthreads();
        #pragma unroll
        for (int kk = 0; kk < 32; ++kk) {
            float b0 = Bs[kk][cg * 2 + 0];
            float b1 = Bs[kk][cg * 2 + 1];
            #pragma unroll
            for (int j = 0; j < 4; ++j) {
                float a = As[rg * 4 + j][kk];
                acc[j][0] = fmaf(a, b0, acc[j][0]);
                acc[j][1] = fmaf(a, b1, acc[j][1]);
            }
        }
        __syncthreads();
    }
    float m0 = fmaxf(fmaxf(acc[0][0], acc[1][0]), fmaxf(acc[2][0], acc[3][0]));
    float m1 = fmaxf(fmaxf(acc[0][1], acc[1][1]), fmaxf(acc[2][1], acc[3][1]));
    red[rg][cg * 2 + 0] = m0;
    red[rg][cg * 2 + 1] = m1;
    __syncthreads();
    if (t < 64) {
        float v = red[0][t];
        #pragma unroll
        for (int q = 1; q < 8; ++q) v = fmaxf(v, red[q][t]);
        part[((size_t)b * 16 + mt) * 1024 + col0 + t] = v;
    }
}

// ---------------------------------------------------------------------------
// Final max over the 16 m-tiles per cloud + bias.
// ---------------------------------------------------------------------------
__global__ __launch_bounds__(256)
void rmax_kernel(const float* __restrict__ part, const float* __restrict__ b3b,
                 float* __restrict__ out) {
    int i = blockIdx.x * 256 + threadIdx.x;  // 8192 = B*1024
    int b = i >> 10, c = i & 1023;
    float v = -__builtin_inff();
    #pragma unroll
    for (int tt = 0; tt < 16; ++tt)
        v = fmaxf(v, part[((size_t)b * 16 + tt) * 1024 + c]);
    out[i] = v + b3b[c];
}

// ---------------------------------------------------------------------------
extern "C" void kernel_launch(void* const* d_in, const int* in_sizes, int n_in,
                              void* d_out, int out_size, void* d_ws, size_t ws_size,
                              hipStream_t stream) {
    const float* pos = (const float*)d_in[0];
    const float* w1a = (const float*)d_in[1];
    const float* b1a = (const float*)d_in[2];
    const float* w1b = (const float*)d_in[3];
    const float* b1b = (const float*)d_in[4];
    const float* w2a = (const float*)d_in[5];
    const float* b2a = (const float*)d_in[6];
    const float* w2b = (const float*)d_in[7];
    const float* b2b = (const float*)d_in[8];
    const float* w3a = (const float*)d_in[9];
    const float* b3a = (const float*)d_in[10];
    const float* w3b = (const float*)d_in[11];
    const float* b3b = (const float*)d_in[12];
    float* out = (float*)d_out;

    char* ws = (char*)d_ws;
    size_t off = 0;
    auto alloc = [&](size_t bytes) -> char* {
        char* p = ws + off;
        off += (bytes + 255) & ~(size_t)255;
        return p;
    };
    float*  c1     = (float*)alloc(sizeof(float) * Bc * M1 * 3);
    float*  c2     = (float*)alloc(sizeof(float) * Bc * M2 * 3);
    float*  x1     = (float*)alloc(sizeof(float) * Bc * M1 * 64);
    float*  X      = (float*)alloc(sizeof(float) * Bc * M2 * LDX);
    float*  H      = (float*)alloc(sizeof(float) * Bc * M2 * 256);
    float*  part   = (float*)alloc(sizeof(float) * Bc * 16 * 1024);
    float*  w1aT   = (float*)alloc(sizeof(float) * 64 * 4);
    float*  w1bT   = (float*)alloc(sizeof(float) * 64 * 64);
    float*  w2aT   = (float*)alloc(sizeof(float) * 128 * 80);
    float*  w2bT   = (float*)alloc(sizeof(float) * 128 * 128);
    float4* scp1_g = (float4*)alloc(sizeof(float4) * Bc * Np);
    float*  mind1g = (float*)alloc(sizeof(float) * Bc * Np);
    float4* scp2_g = (float4*)alloc(sizeof(float4) * Bc * M1);
    float*  mind2g = (float*)alloc(sizeof(float) * Bc * M1);

    auto launch = [&](int grid, int fs, int sb, int se, int wsg, int wbg, int wsh) {
        stage_kernel<<<dim3(grid), dim3(512), 0, stream>>>(
            fs, sb, se, wsg, wbg, wsh,
            pos, c1, c2, X, x1, scp1_g, mind1g, scp2_g, mind2g,
            w1a, b1a, w1b, w2a, b2a, w2b, w1aT, w1bT, w2aT, w2bT, b1b, b2b);
    };

    // LA: fps1 chunk [0,512) + weight prep
    launch(Bc + 32, 1, 0, 512, 1, 0, 0);
    // LB1..3: fps1 chunks + workers1 for the previous chunk (span 512)
    launch(Bc + 240, 1, 512, 1024, 2, 0, 9);
    launch(Bc + 240, 1, 1024, 1536, 2, 512, 9);
    launch(Bc + 240, 1, 1536, 2048, 2, 1024, 9);
    // LC: fps2 chunk [0,256) + workers1 for fps1 chunk 3 (span 512)
    launch(Bc + 240, 2, 0, 256, 2, 1536, 9);
    // LD: fps2 chunk [256,512) + workers2 for fps2 chunk 0 (span 256)
    launch(Bc + 240, 2, 256, 512, 3, 0, 8);
    // LE: workers2 for fps2 chunk 1 (span 256)
    launch(240, 0, 0, 0, 3, 256, 8);

    gemm1_kernel<<<dim3(Bc * M2), dim3(256), 0, stream>>>(X, w3a, b3a, H);
    gemm2_kernel<<<dim3(Bc * 16 * 16), dim3(256), 0, stream>>>(H, w3b, part);
    rmax_kernel<<<dim3(32), dim3(256), 0, stream>>>(part, b3b, out);
}

// Round 7
// 3404.747 us; speedup vs baseline: 1.0008x; 1.0008x over previous
//
#include <hip/hip_runtime.h>
#include <cstdint>
#include <cstddef>

// ---------------------------------------------------------------------------
// PointNet++ (B=8, N=4096, K=64, N1=2048, N2=512, r1=0.2, r2=0.4), fp32.
// Selection stages (FPS argmax, ball-query top-k) use __f*_rn intrinsics in
// numpy's association order -> selected index sets match bit-exactly.
// R16: fix R15's scratch-spill regression. R15 counters: worker dispatches
// 840us @ 230GB/s, WRITE_SIZE 119MB, VGPR=128 -> bq's ub[64] spilled to
// scratch (~47KB/task x 4096 tasks = the entire 193MB of HBM traffic).
// The kernel is LDS-limited to 1 block/CU (94720B) = 2 waves/SIMD, so
// __launch_bounds__(512, 2) is honest and raises the VGPR cap to 256:
// ub[64] + CAP-path arrays fit in registers, zero spill. No algorithmic
// change vs R15 (which passed with absmax 0.0).
// R15: chunked-FPS overlap, stream-ordered deps only. fps1 = 4 chunks of
// 512 selections, fps2 = 2 chunks of 256; each launch = 8 fps-chunk blocks
// + 240 worker blocks running fused bq+mlp for the PREVIOUS chunk's centers.
// Chunk state: sorted scp (float4) persisted once; per-thread mind[] saved
// per chunk; candidate key recomputed at chunk start (bit-exact invariant).
// nbr arrays eliminated (bq writes LDS, mlp consumes in-wave).
// R13: R9 combine (slots[3] + lane63 atomicMax + u64 DPP); float4-packed
// sorted coords+key so the dependent coord lookup is one ds_read_b128.
// R5 core: exact lazy pruning; Morton-bucket-sorted points; per-thread bbox
// lower bound skips the recompute when it cannot change any mind[j].
// Key = (d2bits<<24)|((~orig&0xFFF)<<12)|sortedpos.
// ---------------------------------------------------------------------------

static constexpr int Bc = 8;     // batch (clouds)
static constexpr int Np = 4096;  // points per cloud
static constexpr int Kn = 64;    // max neighbors
static constexpr int M1 = 2048;  // SA1 centers
static constexpr int M2 = 512;   // SA2 centers
static constexpr int LDX = 132;  // row stride of X = [x2 (128) | c2 (3) | pad]

#define DEVINL __device__ __forceinline__

// exact replication of np: ((dx*dx + dy*dy) + dz*dz), no fma contraction
DEVINL float d2_exact(float ax, float ay, float az, float bx, float by, float bz) {
    float dx = __fsub_rn(ax, bx);
    float dy = __fsub_rn(ay, by);
    float dz = __fsub_rn(az, bz);
    float xx = __fmul_rn(dx, dx);
    float yy = __fmul_rn(dy, dy);
    float zz = __fmul_rn(dz, dz);
    return __fadd_rn(__fadd_rn(xx, yy), zz);
}

template <int CTRL, int RM, int BM>
DEVINL unsigned long long dpp_max_step(unsigned long long k) {
    unsigned lo = (unsigned)k, hi = (unsigned)(k >> 32);
    unsigned slo = (unsigned)__builtin_amdgcn_update_dpp(0, (int)lo, CTRL, RM, BM, true);
    unsigned shi = (unsigned)__builtin_amdgcn_update_dpp(0, (int)hi, CTRL, RM, BM, true);
    unsigned long long s = ((unsigned long long)shi << 32) | (unsigned long long)slo;
    return s > k ? s : k;
}

DEVINL unsigned long long wave_max_u64_dpp(unsigned long long k) {
    k = dpp_max_step<0x111, 0xf, 0xf>(k);  // row_shr:1
    k = dpp_max_step<0x112, 0xf, 0xf>(k);  // row_shr:2
    k = dpp_max_step<0x114, 0xf, 0xf>(k);  // row_shr:4
    k = dpp_max_step<0x118, 0xf, 0xf>(k);  // row_shr:8
    k = dpp_max_step<0x142, 0xa, 0xf>(k);  // row_bcast:15
    k = dpp_max_step<0x143, 0xc, 0xf>(k);  // row_bcast:31 -> lane 63 = wave max
    return k;
}

DEVINL unsigned mort3(unsigned v) {  // 3 bits -> bits 0,3,6
    return (v & 1u) | ((v & 2u) << 2) | ((v & 4u) << 4);
}

DEVINL unsigned cell_of(float x, float y, float z) {
    int ix = (int)(x * 8.0f); ix = ix < 0 ? 0 : (ix > 7 ? 7 : ix);
    int iy = (int)(y * 8.0f); iy = iy < 0 ? 0 : (iy > 7 ? 7 : iy);
    int iz = (int)(z * 8.0f); iz = iz < 0 ? 0 : (iz > 7 ? 7 : iz);
    return mort3((unsigned)ix) | (mort3((unsigned)iy) << 1) | (mort3((unsigned)iz) << 2);
}

// inclusive Hillis-Steele scan over 512 entries, 512 threads. 9 barriers.
DEVINL unsigned* scan512(unsigned* h0, unsigned* h1, int t) {
    unsigned* src = h0; unsigned* dst = h1;
    for (int d = 1; d < 512; d <<= 1) {
        unsigned v = src[t];
        if (t >= d) v += src[t - d];
        dst[t] = v;
        __syncthreads();
        unsigned* tmp = src; src = dst; dst = tmp;
    }
    return src;
}

// ---------------------------------------------------------------------------
// FPS chunk: selections [s_begin, s_end) for one cloud. 512 threads.
// NPTS points, PT = NPTS/512 per thread. State in scp_g (sorted, persisted at
// chunk 0) and mind_g (per-thread min distances, saved every chunk).
// Journal (LDS) holds the chunk's selected coords for the caller to flush.
// ---------------------------------------------------------------------------
template <int NPTS, int PT>
DEVINL void fps_chunk_body(const float* __restrict__ srcpts,
                           float4* __restrict__ scp_g,
                           float* __restrict__ mind_g,
                           char* smem, int t, int lane,
                           int s_begin, int s_end) {
    constexpr int NT = NPTS / PT;   // 512
    float4* scp = (float4*)smem;
    unsigned* h0 = (unsigned*)(smem + 65536);
    unsigned* h1 = (unsigned*)(smem + 67584);
    unsigned long long* slots = (unsigned long long*)(smem + 69632);
    float* journal = (float*)(smem + 69664);

    float px[PT], py[PT], pz[PT], mind[PT];
    unsigned oi[PT];
    unsigned long long ck = 0;

    if (s_begin == 0) {
        // -------- chunk 0: load, Morton-bucket sort, persist, seed --------
        float gx[PT], gy[PT], gz[PT];
        unsigned gc[PT];
        #pragma unroll
        for (int j = 0; j < PT; ++j) {
            int p = j * NT + t;
            gx[j] = srcpts[p * 3 + 0];
            gy[j] = srcpts[p * 3 + 1];
            gz[j] = srcpts[p * 3 + 2];
            gc[j] = cell_of(gx[j], gy[j], gz[j]);
        }
        float x0 = srcpts[0], y0 = srcpts[1], z0 = srcpts[2];
        h0[t] = 0;
        if (t == 0) { slots[0] = 0; slots[1] = 0; slots[2] = 0; }
        __syncthreads();
        #pragma unroll
        for (int j = 0; j < PT; ++j) atomicAdd(&h0[gc[j]], 1u);
        __syncthreads();
        unsigned cnt = h0[t];
        unsigned* inc = scan512(h0, h1, t);
        inc[t] -= cnt;
        __syncthreads();
        #pragma unroll
        for (int j = 0; j < PT; ++j) {
            unsigned p = atomicAdd(&inc[gc[j]], 1u);
            unsigned key = ((0xFFFu - (unsigned)(j * NT + t)) << 12) | p;
            scp[p] = make_float4(gx[j], gy[j], gz[j], __uint_as_float(key));
        }
        __syncthreads();
        for (int k = t; k < NPTS; k += NT) scp_g[k] = scp[k];  // persist sort
        #pragma unroll
        for (int j = 0; j < PT; ++j) {
            float4 v = scp[t * PT + j];
            px[j] = v.x; py[j] = v.y; pz[j] = v.z;
            oi[j] = __float_as_uint(v.w);
        }
        #pragma unroll
        for (int j = 0; j < PT; ++j) {
            float d = d2_exact(px[j], py[j], pz[j], x0, y0, z0);
            mind[j] = d;
            unsigned long long kj =
                ((unsigned long long)__float_as_uint(d) << 24) | (unsigned long long)oi[j];
            if (kj > ck) ck = kj;
        }
        if (t == 0) { journal[0] = x0; journal[1] = y0; journal[2] = z0; }
    } else {
        // -------- chunk >0: restore state (bit-exact recompute of ck) -----
        if (t == 0) { slots[0] = 0; slots[1] = 0; slots[2] = 0; }
        for (int k = t; k < NPTS; k += NT) scp[k] = scp_g[k];
        __syncthreads();
        #pragma unroll
        for (int j = 0; j < PT; ++j) {
            float4 v = scp[t * PT + j];
            px[j] = v.x; py[j] = v.y; pz[j] = v.z;
            oi[j] = __float_as_uint(v.w);
        }
        #pragma unroll
        for (int j = 0; j < PT; ++j) mind[j] = mind_g[t * PT + j];
        #pragma unroll
        for (int j = 0; j < PT; ++j) {
            unsigned long long kj =
                ((unsigned long long)__float_as_uint(mind[j]) << 24) |
                (unsigned long long)oi[j];
            if (kj > ck) ck = kj;
        }
    }

    float lox = px[0], hix = px[0], loy = py[0], hiy = py[0], loz = pz[0], hiz = pz[0];
    #pragma unroll
    for (int j = 1; j < PT; ++j) {
        lox = fminf(lox, px[j]); hix = fmaxf(hix, px[j]);
        loy = fminf(loy, py[j]); hiy = fmaxf(hiy, py[j]);
        loz = fminf(loz, pz[j]); hiz = fmaxf(hiz, pz[j]);
    }

    float bmax = __uint_as_float((unsigned)(ck >> 24));
    unsigned long long wkey = wave_max_u64_dpp(ck);
    if (lane == 63) atomicMax(&slots[1], wkey);

    int rd = 1, wr = 2, rs = 0;
    for (int s = (s_begin == 0 ? 1 : s_begin); s < s_end; ++s) {
        __syncthreads();
        unsigned long long km = slots[rd];
        if (t == 0) slots[rs] = 0;
        unsigned spos = (unsigned)km & 0xFFFu;
        float4 cc = scp[spos];
        float cx = cc.x, cy = cc.y, cz = cc.z;
        if (t == 0) {
            int jj = (s - s_begin) * 3;
            journal[jj + 0] = cx; journal[jj + 1] = cy; journal[jj + 2] = cz;
        }
        float dxv = fmaxf(fmaxf(lox - cx, cx - hix), 0.0f);
        float dyv = fmaxf(fmaxf(loy - cy, cy - hiy), 0.0f);
        float dzv = fmaxf(fmaxf(loz - cz, cz - hiz), 0.0f);
        float L = dxv * dxv + dyv * dyv + dzv * dzv;
        bool fire = (L * 0.999f <= bmax);
        if (fire) {
            unsigned long long nck = 0;
            #pragma unroll
            for (int j = 0; j < PT; ++j) {
                float d = d2_exact(px[j], py[j], pz[j], cx, cy, cz);
                float m = fminf(mind[j], d);
                mind[j] = m;
                unsigned long long kj =
                    ((unsigned long long)__float_as_uint(m) << 24) | (unsigned long long)oi[j];
                if (kj > nck) nck = kj;
            }
            ck = nck;
            bmax = __uint_as_float((unsigned)(ck >> 24));
        }
        if (__ballot(fire) != 0ull) wkey = wave_max_u64_dpp(ck);
        if (lane == 63) atomicMax(&slots[wr], wkey);
        int nrd = wr; wr = rs; rs = rd; rd = nrd;
    }
    __syncthreads();   // journal complete; mind final
    #pragma unroll
    for (int j = 0; j < PT; ++j) mind_g[t * PT + j] = mind[j];
}

// ---------------------------------------------------------------------------
// Ball-query core: one wave, one center. d2 per lane in registers; >K in
// radius -> compact to LDS buf + exact kth-smallest binary search. Ties by
// smallest index (== lax.top_k). out is LDS; slots 0..63 filled, -1 pad.
// ---------------------------------------------------------------------------
template <int NPT>
DEVINL void bq_core(const float* __restrict__ pb, float cx, float cy, float cz,
                    float r2, int* out, uint2* buf, int lane) {
    constexpr int CH = NPT / 64;
    constexpr int CAP = 1024;
    const unsigned r2b = __float_as_uint(r2);

    unsigned ub[CH];
    int cnt = 0;
    #pragma unroll
    for (int j = 0; j < CH; ++j) {
        int p = j * 64 + lane;
        float d = d2_exact(pb[p * 3 + 0], pb[p * 3 + 1], pb[p * 3 + 2], cx, cy, cz);
        ub[j] = __float_as_uint(d);   // d >= 0 -> bits monotonic
        cnt += __popcll(__ballot(ub[j] <= r2b));
    }
    const unsigned long long lml = (1ull << lane) - 1ull;

    if (cnt <= Kn) {
        int basep = 0;
        #pragma unroll
        for (int j = 0; j < CH; ++j) {
            bool v = ub[j] <= r2b;
            unsigned long long mk = __ballot(v);
            if (v) out[basep + __popcll(mk & lml)] = j * 64 + lane;
            basep += __popcll(mk);
        }
        if (lane >= cnt) out[lane] = -1;
    } else if (cnt <= CAP) {
        int basep = 0;
        #pragma unroll
        for (int j = 0; j < CH; ++j) {
            bool v = ub[j] <= r2b;
            unsigned long long mk = __ballot(v);
            if (v) buf[basep + __popcll(mk & lml)] =
                       make_uint2(ub[j], (unsigned)(j * 64 + lane));
            basep += __popcll(mk);
        }
        const int C2 = (cnt + 63) >> 6;   // wave-uniform
        unsigned cb[CAP / 64], ci[CAP / 64];
        #pragma unroll
        for (int e = 0; e < CAP / 64; ++e) {
            if (e >= C2) break;
            int p = e * 64 + lane;
            uint2 v = buf[p];
            cb[e] = (p < cnt) ? v.x : 0xFFFFFFFFu;
            ci[e] = v.y;
        }
        unsigned lo = 0, hi = r2b;
        while (lo < hi) {
            unsigned mid = lo + ((hi - lo) >> 1);
            int c = 0;
            #pragma unroll
            for (int e = 0; e < CAP / 64; ++e) {
                if (e >= C2) break;
                c += __popcll(__ballot(cb[e] <= mid));
            }
            if (c >= Kn) hi = mid; else lo = mid + 1;
        }
        const unsigned tt = lo;
        int cntLess = 0;
        #pragma unroll
        for (int e = 0; e < CAP / 64; ++e) {
            if (e >= C2) break;
            cntLess += __popcll(__ballot(cb[e] < tt));
        }
        const int quota = Kn - cntLess;
        int baseLt = 0, eqseen = 0;
        #pragma unroll
        for (int e = 0; e < CAP / 64; ++e) {
            if (e >= C2) break;
            bool lt = cb[e] < tt;
            bool eq = cb[e] == tt;
            unsigned long long mlt = __ballot(lt);
            unsigned long long meq = __ballot(eq);
            if (lt) out[baseLt + __popcll(mlt & lml)] = (int)ci[e];
            if (eq) {
                int rr = eqseen + __popcll(meq & lml);
                if (rr < quota) out[cntLess + rr] = (int)ci[e];
            }
            baseLt += __popcll(mlt);
            eqseen += __popcll(meq);
        }
    } else {
        unsigned lo = 0, hi = r2b;
        while (lo < hi) {
            unsigned mid = lo + ((hi - lo) >> 1);
            int c = 0;
            #pragma unroll
            for (int j = 0; j < CH; ++j) c += __popcll(__ballot(ub[j] <= mid));
            if (c >= Kn) hi = mid; else lo = mid + 1;
        }
        const unsigned tt = lo;
        int cntLess = 0;
        #pragma unroll
        for (int j = 0; j < CH; ++j) cntLess += __popcll(__ballot(ub[j] < tt));
        const int quota = Kn - cntLess;
        int baseLt = 0, eqseen = 0;
        #pragma unroll
        for (int j = 0; j < CH; ++j) {
            bool lt = ub[j] < tt;
            bool eq = ub[j] == tt;
            unsigned long long mlt = __ballot(lt);
            unsigned long long meq = __ballot(eq);
            if (lt) out[baseLt + __popcll(mlt & lml)] = j * 64 + lane;
            if (eq) {
                int rr = eqseen + __popcll(meq & lml);
                if (rr < quota) out[cntLess + rr] = j * 64 + lane;
            }
            baseLt += __popcll(mlt);
            eqseen += __popcll(meq);
        }
    }
}

// ---------------------------------------------------------------------------
// MLP1 core (wave, one center): 3 -> 64 relu -> 64 relu, masked max.
// ---------------------------------------------------------------------------
DEVINL void mlp1_core(const float* __restrict__ pb, float cx, float cy, float cz,
                      const int* nbrL, const float* __restrict__ w1aT,
                      const float* __restrict__ w1bT, const float* __restrict__ b1b,
                      float* __restrict__ orow, int lane) {
    const int ii = nbrL[lane];
    const bool valid = ii >= 0;
    const int i2 = valid ? ii : 0;
    const float* pp = pb + (size_t)i2 * 3;
    float rx = pp[0] - cx, ry = pp[1] - cy, rz = pp[2] - cz;
    float h1[64];
    #pragma unroll
    for (int h = 0; h < 64; ++h) {
        float4 wv = ((const float4*)w1aT)[h];
        float a = fmaf(rx, wv.x, fmaf(ry, wv.y, fmaf(rz, wv.z, wv.w)));
        h1[h] = fmaxf(a, 0.0f);
    }
    for (int c4 = 0; c4 < 16; ++c4) {
        float v4[4];
        #pragma unroll
        for (int cq = 0; cq < 4; ++cq) {
            int c = c4 * 4 + cq;
            float acc = b1b[c];
            const float4* wr = (const float4*)(w1bT + (size_t)c * 64);
            #pragma unroll
            for (int q = 0; q < 16; ++q) {
                float4 wv = wr[q];
                acc = fmaf(h1[4 * q + 0], wv.x, acc);
                acc = fmaf(h1[4 * q + 1], wv.y, acc);
                acc = fmaf(h1[4 * q + 2], wv.z, acc);
                acc = fmaf(h1[4 * q + 3], wv.w, acc);
            }
            float v = fmaxf(acc, 0.0f);
            v = valid ? v : -__builtin_inff();
            #pragma unroll
            for (int o = 32; o > 0; o >>= 1) v = fmaxf(v, __shfl_xor(v, o, 64));
            v4[cq] = v;
        }
        if (lane == 0)
            ((float4*)orow)[c4] = make_float4(v4[0], v4[1], v4[2], v4[3]);
    }
}

// ---------------------------------------------------------------------------
// MLP2 core (wave, one center): [x1(64)|relpos(3)] -> 128 relu -> 128 relu,
// masked max; writes X row cols 0..127.
// ---------------------------------------------------------------------------
DEVINL void mlp2_core(const float* __restrict__ x1b, const float* __restrict__ c1b,
                      float cx, float cy, float cz, const int* nbrL,
                      const float* __restrict__ w2aT, const float* __restrict__ w2bT,
                      const float* __restrict__ b2b, float* __restrict__ orow,
                      int lane) {
    const int ii = nbrL[lane];
    const bool valid = ii >= 0;
    const int i2 = valid ? ii : 0;

    float x[68];
    const float4* xr = (const float4*)(x1b + (size_t)i2 * 64);
    #pragma unroll
    for (int q = 0; q < 16; ++q) {
        float4 v = xr[q];
        x[4 * q + 0] = v.x; x[4 * q + 1] = v.y;
        x[4 * q + 2] = v.z; x[4 * q + 3] = v.w;
    }
    const float* cp = c1b + (size_t)i2 * 3;
    x[64] = cp[0] - cx;
    x[65] = cp[1] - cy;
    x[66] = cp[2] - cz;
    x[67] = 0.0f;

    float h1[128];
    #pragma unroll
    for (int h = 0; h < 128; ++h) {
        const float4* r4 = (const float4*)(w2aT + (size_t)h * 80);
        float acc = 0.0f;
        #pragma unroll
        for (int q = 0; q < 16; ++q) {
            float4 wv = r4[q];
            acc = fmaf(x[4 * q + 0], wv.x, acc);
            acc = fmaf(x[4 * q + 1], wv.y, acc);
            acc = fmaf(x[4 * q + 2], wv.z, acc);
            acc = fmaf(x[4 * q + 3], wv.w, acc);
        }
        float4 tl = r4[16];   // w64, w65, w66, bias
        acc = fmaf(x[64], tl.x, acc);
        acc = fmaf(x[65], tl.y, acc);
        acc = fmaf(x[66], tl.z, acc);
        acc += tl.w;
        h1[h] = fmaxf(acc, 0.0f);
    }
    for (int c4 = 0; c4 < 32; ++c4) {
        float v4[4];
        #pragma unroll
        for (int cq = 0; cq < 4; ++cq) {
            int c = c4 * 4 + cq;
            float acc = b2b[c];
            const float4* wr = (const float4*)(w2bT + (size_t)c * 128);
            #pragma unroll
            for (int q = 0; q < 32; ++q) {
                float4 wv = wr[q];
                acc = fmaf(h1[4 * q + 0], wv.x, acc);
                acc = fmaf(h1[4 * q + 1], wv.y, acc);
                acc = fmaf(h1[4 * q + 2], wv.z, acc);
                acc = fmaf(h1[4 * q + 3], wv.w, acc);
            }
            float v = fmaxf(acc, 0.0f);
            v = valid ? v : -__builtin_inff();
            #pragma unroll
            for (int o = 32; o > 0; o >>= 1) v = fmaxf(v, __shfl_xor(v, o, 64));
            v4[cq] = v;
        }
        if (lane == 0) {
            orow[c4 * 4 + 0] = v4[0]; orow[c4 * 4 + 1] = v4[1];
            orow[c4 * 4 + 2] = v4[2]; orow[c4 * 4 + 3] = v4[3];
        }
    }
}

// ---------------------------------------------------------------------------
// stage_kernel: 512 threads, LDS 94720 -> 1 block/CU = 2 waves/SIMD, so
// __launch_bounds__(512, 2) (VGPR cap 256, no spill -- the R15 fix).
//  fps_stage: 1 = fps1 chunk (blocks 0..7), 2 = fps2 chunk, 0 = none.
//  w_stage:   1 = weight prep, 2 = workers1 (bq1+mlp1), 3 = workers2
//             (bq2+mlp2), 0 = none. Worker blocks follow the fps blocks.
//  Workers handle centers [w_begin, w_begin + (1<<wsh)) for all 8 clouds.
//  All inter-role dependencies are across LAUNCHES (stream-ordered).
// ---------------------------------------------------------------------------
__global__ __launch_bounds__(512, 2)
void stage_kernel(int fps_stage, int s_begin, int s_end,
                  int w_stage, int w_begin, int wsh,
                  const float* __restrict__ pos, float* __restrict__ c1,
                  float* __restrict__ c2, float* __restrict__ X,
                  float* __restrict__ x1,
                  float4* __restrict__ scp1_g, float* __restrict__ mind1_g,
                  float4* __restrict__ scp2_g, float* __restrict__ mind2_g,
                  const float* __restrict__ w1a, const float* __restrict__ b1a,
                  const float* __restrict__ w1b, const float* __restrict__ w2a,
                  const float* __restrict__ b2a, const float* __restrict__ w2b,
                  float* __restrict__ w1aT, float* __restrict__ w1bT,
                  float* __restrict__ w2aT, float* __restrict__ w2bT,
                  const float* __restrict__ b1b, const float* __restrict__ b2b) {
    __shared__ __align__(16) char smem[94720];
    const int t = threadIdx.x;
    const int lane = t & 63;
    const int wid = t >> 6;

    if (fps_stage > 0 && blockIdx.x < Bc) {
        const int b = blockIdx.x;
        float* journal = (float*)(smem + 69664);
        if (fps_stage == 1) {
            fps_chunk_body<Np, 8>(pos + (size_t)b * Np * 3, scp1_g + (size_t)b * Np,
                                  mind1_g + (size_t)b * Np, smem, t, lane,
                                  s_begin, s_end);
            int n = (s_end - s_begin) * 3;
            for (int i = t; i < n; i += 512)
                c1[(size_t)b * M1 * 3 + s_begin * 3 + i] = journal[i];
        } else {
            fps_chunk_body<M1, 4>(c1 + (size_t)b * M1 * 3, scp2_g + (size_t)b * M1,
                                  mind2_g + (size_t)b * M1, smem, t, lane,
                                  s_begin, s_end);
            int n = (s_end - s_begin) * 3;
            for (int i = t; i < n; i += 512)
                c2[(size_t)b * M2 * 3 + s_begin * 3 + i] = journal[i];
            for (int i = t; i < n; i += 512) {
                int s = i / 3, k = i - s * 3;
                X[(size_t)(b * M2 + s_begin + s) * LDX + 128 + k] = journal[i];
            }
        }
        return;
    }

    const int wb = (fps_stage > 0) ? (int)blockIdx.x - Bc : (int)blockIdx.x;
    const int nw = (fps_stage > 0) ? (int)gridDim.x - Bc : (int)gridDim.x;

    if (w_stage == 1) {
        // ---------------- weight-transpose prep ----------------
        int i = wb * 512 + t;  // 0..16383
        if (i < 64 * 4) {
            int h = i >> 2, d = i & 3;
            w1aT[i] = (d < 3) ? w1a[d * 64 + h] : b1a[h];
        }
        if (i < 64 * 64) {
            int c = i >> 6, h = i & 63;
            w1bT[i] = w1b[h * 64 + c];
        }
        if (i < 128 * 80) {
            int h = i / 80, d = i - h * 80;
            w2aT[i] = (d < 67) ? w2a[d * 128 + h] : ((d == 67) ? b2a[h] : 0.0f);
        }
        if (i < 128 * 128) {
            int c = i >> 7, h = i & 127;
            w2bT[i] = w2b[h * 128 + c];
        }
        return;
    }

    if (w_stage == 2) {
        // ---------------- workers1: fused bq1 + mlp1 ----------------
        uint2* cbuf = (uint2*)smem + (size_t)wid * 1024;       // 8 KB/wave
        int* nbrL = (int*)(smem + 65536) + wid * 64;
        const int span_mask = (1 << wsh) - 1;
        const int ntasks = Bc << wsh;
        for (int task = wb * 8 + wid; task < ntasks; task += nw * 8) {
            const int b = task >> wsh;
            const int s = w_begin + (task & span_mask);
            const int w = b * M1 + s;
            const float* cr = c1 + (size_t)w * 3;
            float cx = cr[0], cy = cr[1], cz = cr[2];
            const float* pb = pos + (size_t)b * Np * 3;
            bq_core<Np>(pb, cx, cy, cz, (float)(0.2 * 0.2), nbrL, cbuf, lane);
            mlp1_core(pb, cx, cy, cz, nbrL, w1aT, w1bT, b1b,
                      x1 + (size_t)w * 64, lane);
        }
        return;
    }

    if (w_stage == 3) {
        // ---------------- workers2: fused bq2 + mlp2 ----------------
        uint2* cbuf = (uint2*)smem + (size_t)wid * 1024;
        int* nbrL = (int*)(smem + 65536) + wid * 64;
        const int span_mask = (1 << wsh) - 1;
        const int ntasks = Bc << wsh;
        for (int task = wb * 8 + wid; task < ntasks; task += nw * 8) {
            const int b = task >> wsh;
            const int s = w_begin + (task & span_mask);
            const int w = b * M2 + s;
            const float* cr = c2 + (size_t)w * 3;
            float cx = cr[0], cy = cr[1], cz = cr[2];
            const float* c1b = c1 + (size_t)b * M1 * 3;
            bq_core<M1>(c1b, cx, cy, cz, (float)(0.4 * 0.4), nbrL, cbuf, lane);
            mlp2_core(x1 + (size_t)b * M1 * 64, c1b, cx, cy, cz, nbrL,
                      w2aT, w2bT, b2b, X + (size_t)w * LDX, lane);
        }
        return;
    }
}

// ---------------------------------------------------------------------------
// GEMM1: H[r][c] = relu(b3a[c] + sum_i X[r][i] * w3a[i][c]), K=131.
// ---------------------------------------------------------------------------
__global__ __launch_bounds__(256)
void gemm1_kernel(const float* __restrict__ X, const float* __restrict__ w3a,
                  const float* __restrict__ b3a, float* __restrict__ H) {
    const int r = blockIdx.x;
    const int c = threadIdx.x;
    const float* xr = X + (size_t)r * LDX;
    float acc = b3a[c];
    for (int i = 0; i < 131; ++i)
        acc = fmaf(xr[i], w3a[(size_t)i * 256 + c], acc);
    H[(size_t)r * 256 + c] = fmaxf(acc, 0.0f);
}

// ---------------------------------------------------------------------------
// GEMM2 fused with per-tile row max: 32x64 tile, BK=32.
// ---------------------------------------------------------------------------
__global__ __launch_bounds__(256)
void gemm2_kernel(const float* __restrict__ H, const float* __restrict__ w3b,
                  float* __restrict__ part) {
    __shared__ float As[32][33];
    __shared__ float Bs[32][64];
    __shared__ float red[8][64];
    const int bidx = blockIdx.x;
    const int nt = bidx & 15;
    const int mt = (bidx >> 4) & 15;
    const int b = bidx >> 8;
    const int row0 = b * M2 + mt * 32;
    const int col0 = nt * 64;
    const int t = threadIdx.x;
    const int rg = t >> 5, cg = t & 31;

    float acc[4][2] = {{0.f, 0.f}, {0.f, 0.f}, {0.f, 0.f}, {0.f, 0.f}};
    for (int k0 = 0; k0 < 256; k0 += 32) {
        #pragma unroll
        for (int q = 0; q < 4; ++q) {
            int id = t + q * 256;
            As[id >> 5][id & 31] = H[(size_t)(row0 + (id >> 5)) * 256 + k0 + (id & 31)];
        }
        #pragma unroll
        for (int q = 0; q < 8; ++q) {
            int id = t + q * 256;
            Bs[id >> 6][id & 63] = w3b[(size_t)(k0 + (id >> 6)) * 1024 + col0 + (id & 63)];
        }
        __syncthreads();
        #pragma unroll
        for (int kk = 0; kk < 32; ++kk) {
            float b0 = Bs[kk][cg * 2 + 0];
            float b1 = Bs[kk][cg * 2 + 1];
            #pragma unroll
            for (int j = 0; j < 4; ++j) {
                float a = As[rg * 4 + j][kk];
                acc[j][0] = fmaf(a, b0, acc[j][0]);
                acc[j][1] = fmaf(a, b1, acc[j][1]);
            }
        }
        __syncthreads();
    }
    float m0 = fmaxf(fmaxf(acc[0][0], acc[1][0]), fmaxf(acc[2][0], acc[3][0]));
    float m1 = fmaxf(fmaxf(acc[0][1], acc[1][1]), fmaxf(acc[2][1], acc[3][1]));
    red[rg][cg * 2 + 0] = m0;
    red[rg][cg * 2 + 1] = m1;
    __syncthreads();
    if (t < 64) {
        float v = red[0][t];
        #pragma unroll
        for (int q = 1; q < 8; ++q) v = fmaxf(v, red[q][t]);
        part[((size_t)b * 16 + mt) * 1024 + col0 + t] = v;
    }
}

// ---------------------------------------------------------------------------
// Final max over the 16 m-tiles per cloud + bias.
// ---------------------------------------------------------------------------
__global__ __launch_bounds__(256)
void rmax_kernel(const float* __restrict__ part, const float* __restrict__ b3b,
                 float* __restrict__ out) {
    int i = blockIdx.x * 256 + threadIdx.x;  // 8192 = B*1024
    int b = i >> 10, c = i & 1023;
    float v = -__builtin_inff();
    #pragma unroll
    for (int tt = 0; tt < 16; ++tt)
        v = fmaxf(v, part[((size_t)b * 16 + tt) * 1024 + c]);
    out[i] = v + b3b[c];
}

// ---------------------------------------------------------------------------
extern "C" void kernel_launch(void* const* d_in, const int* in_sizes, int n_in,
                              void* d_out, int out_size, void* d_ws, size_t ws_size,
                              hipStream_t stream) {
    const float* pos = (const float*)d_in[0];
    const float* w1a = (const float*)d_in[1];
    const float* b1a = (const float*)d_in[2];
    const float* w1b = (const float*)d_in[3];
    const float* b1b = (const float*)d_in[4];
    const float* w2a = (const float*)d_in[5];
    const float* b2a = (const float*)d_in[6];
    const float* w2b = (const float*)d_in[7];
    const float* b2b = (const float*)d_in[8];
    const float* w3a = (const float*)d_in[9];
    const float* b3a = (const float*)d_in[10];
    const float* w3b = (const float*)d_in[11];
    const float* b3b = (const float*)d_in[12];
    float* out = (float*)d_out;

    char* ws = (char*)d_ws;
    size_t off = 0;
    auto alloc = [&](size_t bytes) -> char* {
        char* p = ws + off;
        off += (bytes + 255) & ~(size_t)255;
        return p;
    };
    float*  c1     = (float*)alloc(sizeof(float) * Bc * M1 * 3);
    float*  c2     = (float*)alloc(sizeof(float) * Bc * M2 * 3);
    float*  x1     = (float*)alloc(sizeof(float) * Bc * M1 * 64);
    float*  X      = (float*)alloc(sizeof(float) * Bc * M2 * LDX);
    float*  H      = (float*)alloc(sizeof(float) * Bc * M2 * 256);
    float*  part   = (float*)alloc(sizeof(float) * Bc * 16 * 1024);
    float*  w1aT   = (float*)alloc(sizeof(float) * 64 * 4);
    float*  w1bT   = (float*)alloc(sizeof(float) * 64 * 64);
    float*  w2aT   = (float*)alloc(sizeof(float) * 128 * 80);
    float*  w2bT   = (float*)alloc(sizeof(float) * 128 * 128);
    float4* scp1_g = (float4*)alloc(sizeof(float4) * Bc * Np);
    float*  mind1g = (float*)alloc(sizeof(float) * Bc * Np);
    float4* scp2_g = (float4*)alloc(sizeof(float4) * Bc * M1);
    float*  mind2g = (float*)alloc(sizeof(float) * Bc * M1);

    auto launch = [&](int grid, int fs, int sb, int se, int wsg, int wbg, int wsh) {
        stage_kernel<<<dim3(grid), dim3(512), 0, stream>>>(
            fs, sb, se, wsg, wbg, wsh,
            pos, c1, c2, X, x1, scp1_g, mind1g, scp2_g, mind2g,
            w1a, b1a, w1b, w2a, b2a, w2b, w1aT, w1bT, w2aT, w2bT, b1b, b2b);
    };

    // LA: fps1 chunk [0,512) + weight prep
    launch(Bc + 32, 1, 0, 512, 1, 0, 0);
    // LB1..3: fps1 chunks + workers1 for the previous chunk (span 512)
    launch(Bc + 240, 1, 512, 1024, 2, 0, 9);
    launch(Bc + 240, 1, 1024, 1536, 2, 512, 9);
    launch(Bc + 240, 1, 1536, 2048, 2, 1024, 9);
    // LC: fps2 chunk [0,256) + workers1 for fps1 chunk 3 (span 512)
    launch(Bc + 240, 2, 0, 256, 2, 1536, 9);
    // LD: fps2 chunk [256,512) + workers2 for fps2 chunk 0 (span 256)
    launch(Bc + 240, 2, 256, 512, 3, 0, 8);
    // LE: workers2 for fps2 chunk 1 (span 256)
    launch(240, 0, 0, 0, 3, 256, 8);

    gemm1_kernel<<<dim3(Bc * M2), dim3(256), 0, stream>>>(X, w3a, b3a, H);
    gemm2_kernel<<<dim3(Bc * 16 * 16), dim3(256), 0, stream>>>(H, w3b, part);
    rmax_kernel<<<dim3(32), dim3(256), 0, stream>>>(part, b3b, out);
}

// Round 8
// 2716.966 us; speedup vs baseline: 1.2541x; 1.2531x over previous
//
#include <hip/hip_runtime.h>
#include <cstdint>
#include <cstddef>

// ---------------------------------------------------------------------------
// PointNet++ (B=8, N=4096, K=64, N1=2048, N2=512, r1=0.2, r2=0.4), fp32.
// Selection stages (FPS argmax, ball-query top-k) use __f*_rn intrinsics in
// numpy's association order -> selected index sets match bit-exactly.
// R17: kill the worker scratch-spill for real. R16 evidence: VGPR_Count
// stayed 128 (launch_bounds min-waves only caps VGPRs, it does not lower the
// allocator's occupancy TARGET of 4 waves/EU, so it spilled to hit it).
//  (a) __attribute__((amdgpu_waves_per_eu(2,2))) pins target = 2 waves/EU
//      (the LDS-forced occupancy) -> VGPR budget 256, no spill.
//  (b) bq_core restructured to drop persistent ub[64]: pass 1 counts only;
//      pass 2 recomputes d2_exact (pure -> bit-identical) and emits/compacts.
//      Worker-1 peak regs ~110 -> fits even a 128 cap. >CAP fallback
//      recomputes per bisection step (never taken; kept exact).
// R15: chunked-FPS overlap, stream-ordered deps only. fps1 = 4 chunks of
// 512 selections, fps2 = 2 chunks of 256; each launch = 8 fps-chunk blocks
// + 240 worker blocks running fused bq+mlp for the PREVIOUS chunk's centers.
// Chunk state: sorted scp (float4) persisted once; per-thread mind[] saved
// per chunk; candidate key recomputed at chunk start (bit-exact invariant).
// nbr arrays eliminated (bq writes LDS, mlp consumes in-wave).
// R13: R9 combine (slots[3] + lane63 atomicMax + u64 DPP); float4-packed
// sorted coords+key so the dependent coord lookup is one ds_read_b128.
// R5 core: exact lazy pruning; Morton-bucket-sorted points; per-thread bbox
// lower bound skips the recompute when it cannot change any mind[j].
// Key = (d2bits<<24)|((~orig&0xFFF)<<12)|sortedpos.
// ---------------------------------------------------------------------------

static constexpr int Bc = 8;     // batch (clouds)
static constexpr int Np = 4096;  // points per cloud
static constexpr int Kn = 64;    // max neighbors
static constexpr int M1 = 2048;  // SA1 centers
static constexpr int M2 = 512;   // SA2 centers
static constexpr int LDX = 132;  // row stride of X = [x2 (128) | c2 (3) | pad]

#define DEVINL __device__ __forceinline__

// exact replication of np: ((dx*dx + dy*dy) + dz*dz), no fma contraction
DEVINL float d2_exact(float ax, float ay, float az, float bx, float by, float bz) {
    float dx = __fsub_rn(ax, bx);
    float dy = __fsub_rn(ay, by);
    float dz = __fsub_rn(az, bz);
    float xx = __fmul_rn(dx, dx);
    float yy = __fmul_rn(dy, dy);
    float zz = __fmul_rn(dz, dz);
    return __fadd_rn(__fadd_rn(xx, yy), zz);
}

template <int CTRL, int RM, int BM>
DEVINL unsigned long long dpp_max_step(unsigned long long k) {
    unsigned lo = (unsigned)k, hi = (unsigned)(k >> 32);
    unsigned slo = (unsigned)__builtin_amdgcn_update_dpp(0, (int)lo, CTRL, RM, BM, true);
    unsigned shi = (unsigned)__builtin_amdgcn_update_dpp(0, (int)hi, CTRL, RM, BM, true);
    unsigned long long s = ((unsigned long long)shi << 32) | (unsigned long long)slo;
    return s > k ? s : k;
}

DEVINL unsigned long long wave_max_u64_dpp(unsigned long long k) {
    k = dpp_max_step<0x111, 0xf, 0xf>(k);  // row_shr:1
    k = dpp_max_step<0x112, 0xf, 0xf>(k);  // row_shr:2
    k = dpp_max_step<0x114, 0xf, 0xf>(k);  // row_shr:4
    k = dpp_max_step<0x118, 0xf, 0xf>(k);  // row_shr:8
    k = dpp_max_step<0x142, 0xa, 0xf>(k);  // row_bcast:15
    k = dpp_max_step<0x143, 0xc, 0xf>(k);  // row_bcast:31 -> lane 63 = wave max
    return k;
}

DEVINL unsigned mort3(unsigned v) {  // 3 bits -> bits 0,3,6
    return (v & 1u) | ((v & 2u) << 2) | ((v & 4u) << 4);
}

DEVINL unsigned cell_of(float x, float y, float z) {
    int ix = (int)(x * 8.0f); ix = ix < 0 ? 0 : (ix > 7 ? 7 : ix);
    int iy = (int)(y * 8.0f); iy = iy < 0 ? 0 : (iy > 7 ? 7 : iy);
    int iz = (int)(z * 8.0f); iz = iz < 0 ? 0 : (iz > 7 ? 7 : iz);
    return mort3((unsigned)ix) | (mort3((unsigned)iy) << 1) | (mort3((unsigned)iz) << 2);
}

// inclusive Hillis-Steele scan over 512 entries, 512 threads. 9 barriers.
DEVINL unsigned* scan512(unsigned* h0, unsigned* h1, int t) {
    unsigned* src = h0; unsigned* dst = h1;
    for (int d = 1; d < 512; d <<= 1) {
        unsigned v = src[t];
        if (t >= d) v += src[t - d];
        dst[t] = v;
        __syncthreads();
        unsigned* tmp = src; src = dst; dst = tmp;
    }
    return src;
}

// ---------------------------------------------------------------------------
// FPS chunk: selections [s_begin, s_end) for one cloud. 512 threads.
// NPTS points, PT = NPTS/512 per thread. State in scp_g (sorted, persisted at
// chunk 0) and mind_g (per-thread min distances, saved every chunk).
// Journal (LDS) holds the chunk's selected coords for the caller to flush.
// ---------------------------------------------------------------------------
template <int NPTS, int PT>
DEVINL void fps_chunk_body(const float* __restrict__ srcpts,
                           float4* __restrict__ scp_g,
                           float* __restrict__ mind_g,
                           char* smem, int t, int lane,
                           int s_begin, int s_end) {
    constexpr int NT = NPTS / PT;   // 512
    float4* scp = (float4*)smem;
    unsigned* h0 = (unsigned*)(smem + 65536);
    unsigned* h1 = (unsigned*)(smem + 67584);
    unsigned long long* slots = (unsigned long long*)(smem + 69632);
    float* journal = (float*)(smem + 69664);

    float px[PT], py[PT], pz[PT], mind[PT];
    unsigned oi[PT];
    unsigned long long ck = 0;

    if (s_begin == 0) {
        // -------- chunk 0: load, Morton-bucket sort, persist, seed --------
        float gx[PT], gy[PT], gz[PT];
        unsigned gc[PT];
        #pragma unroll
        for (int j = 0; j < PT; ++j) {
            int p = j * NT + t;
            gx[j] = srcpts[p * 3 + 0];
            gy[j] = srcpts[p * 3 + 1];
            gz[j] = srcpts[p * 3 + 2];
            gc[j] = cell_of(gx[j], gy[j], gz[j]);
        }
        float x0 = srcpts[0], y0 = srcpts[1], z0 = srcpts[2];
        h0[t] = 0;
        if (t == 0) { slots[0] = 0; slots[1] = 0; slots[2] = 0; }
        __syncthreads();
        #pragma unroll
        for (int j = 0; j < PT; ++j) atomicAdd(&h0[gc[j]], 1u);
        __syncthreads();
        unsigned cnt = h0[t];
        unsigned* inc = scan512(h0, h1, t);
        inc[t] -= cnt;
        __syncthreads();
        #pragma unroll
        for (int j = 0; j < PT; ++j) {
            unsigned p = atomicAdd(&inc[gc[j]], 1u);
            unsigned key = ((0xFFFu - (unsigned)(j * NT + t)) << 12) | p;
            scp[p] = make_float4(gx[j], gy[j], gz[j], __uint_as_float(key));
        }
        __syncthreads();
        for (int k = t; k < NPTS; k += NT) scp_g[k] = scp[k];  // persist sort
        #pragma unroll
        for (int j = 0; j < PT; ++j) {
            float4 v = scp[t * PT + j];
            px[j] = v.x; py[j] = v.y; pz[j] = v.z;
            oi[j] = __float_as_uint(v.w);
        }
        #pragma unroll
        for (int j = 0; j < PT; ++j) {
            float d = d2_exact(px[j], py[j], pz[j], x0, y0, z0);
            mind[j] = d;
            unsigned long long kj =
                ((unsigned long long)__float_as_uint(d) << 24) | (unsigned long long)oi[j];
            if (kj > ck) ck = kj;
        }
        if (t == 0) { journal[0] = x0; journal[1] = y0; journal[2] = z0; }
    } else {
        // -------- chunk >0: restore state (bit-exact recompute of ck) -----
        if (t == 0) { slots[0] = 0; slots[1] = 0; slots[2] = 0; }
        for (int k = t; k < NPTS; k += NT) scp[k] = scp_g[k];
        __syncthreads();
        #pragma unroll
        for (int j = 0; j < PT; ++j) {
            float4 v = scp[t * PT + j];
            px[j] = v.x; py[j] = v.y; pz[j] = v.z;
            oi[j] = __float_as_uint(v.w);
        }
        #pragma unroll
        for (int j = 0; j < PT; ++j) mind[j] = mind_g[t * PT + j];
        #pragma unroll
        for (int j = 0; j < PT; ++j) {
            unsigned long long kj =
                ((unsigned long long)__float_as_uint(mind[j]) << 24) |
                (unsigned long long)oi[j];
            if (kj > ck) ck = kj;
        }
    }

    float lox = px[0], hix = px[0], loy = py[0], hiy = py[0], loz = pz[0], hiz = pz[0];
    #pragma unroll
    for (int j = 1; j < PT; ++j) {
        lox = fminf(lox, px[j]); hix = fmaxf(hix, px[j]);
        loy = fminf(loy, py[j]); hiy = fmaxf(hiy, py[j]);
        loz = fminf(loz, pz[j]); hiz = fmaxf(hiz, pz[j]);
    }

    float bmax = __uint_as_float((unsigned)(ck >> 24));
    unsigned long long wkey = wave_max_u64_dpp(ck);
    if (lane == 63) atomicMax(&slots[1], wkey);

    int rd = 1, wr = 2, rs = 0;
    for (int s = (s_begin == 0 ? 1 : s_begin); s < s_end; ++s) {
        __syncthreads();
        unsigned long long km = slots[rd];
        if (t == 0) slots[rs] = 0;
        unsigned spos = (unsigned)km & 0xFFFu;
        float4 cc = scp[spos];
        float cx = cc.x, cy = cc.y, cz = cc.z;
        if (t == 0) {
            int jj = (s - s_begin) * 3;
            journal[jj + 0] = cx; journal[jj + 1] = cy; journal[jj + 2] = cz;
        }
        float dxv = fmaxf(fmaxf(lox - cx, cx - hix), 0.0f);
        float dyv = fmaxf(fmaxf(loy - cy, cy - hiy), 0.0f);
        float dzv = fmaxf(fmaxf(loz - cz, cz - hiz), 0.0f);
        float L = dxv * dxv + dyv * dyv + dzv * dzv;
        bool fire = (L * 0.999f <= bmax);
        if (fire) {
            unsigned long long nck = 0;
            #pragma unroll
            for (int j = 0; j < PT; ++j) {
                float d = d2_exact(px[j], py[j], pz[j], cx, cy, cz);
                float m = fminf(mind[j], d);
                mind[j] = m;
                unsigned long long kj =
                    ((unsigned long long)__float_as_uint(m) << 24) | (unsigned long long)oi[j];
                if (kj > nck) nck = kj;
            }
            ck = nck;
            bmax = __uint_as_float((unsigned)(ck >> 24));
        }
        if (__ballot(fire) != 0ull) wkey = wave_max_u64_dpp(ck);
        if (lane == 63) atomicMax(&slots[wr], wkey);
        int nrd = wr; wr = rs; rs = rd; rd = nrd;
    }
    __syncthreads();   // journal complete; mind final
    #pragma unroll
    for (int j = 0; j < PT; ++j) mind_g[t * PT + j] = mind[j];
}

// ---------------------------------------------------------------------------
// Ball-query core (no persistent ub[] -- R17): pass 1 counts; pass 2
// RECOMPUTES d2_exact (pure -> bit-identical) and emits/compacts. >K in
// radius -> compact to LDS buf + exact kth-smallest binary search. Ties by
// smallest index (== lax.top_k). out is LDS; slots 0..63 filled, -1 pad.
// ---------------------------------------------------------------------------
template <int NPT>
DEVINL void bq_core(const float* __restrict__ pb, float cx, float cy, float cz,
                    float r2, int* out, uint2* buf, int lane) {
    constexpr int CH = NPT / 64;
    constexpr int CAP = 1024;
    const unsigned r2b = __float_as_uint(r2);
    const unsigned long long lml = (1ull << lane) - 1ull;

    // ---- pass 1: count in-radius points (no per-chunk state retained) ----
    int cnt = 0;
    #pragma unroll 8
    for (int j = 0; j < CH; ++j) {
        int p = j * 64 + lane;
        float d = d2_exact(pb[p * 3 + 0], pb[p * 3 + 1], pb[p * 3 + 2], cx, cy, cz);
        cnt += __popcll(__ballot(__float_as_uint(d) <= r2b));
    }

    if (cnt <= Kn) {
        // ---- pass 2: emit indices in index order ----
        int basep = 0;
        #pragma unroll 8
        for (int j = 0; j < CH; ++j) {
            int p = j * 64 + lane;
            float d = d2_exact(pb[p * 3 + 0], pb[p * 3 + 1], pb[p * 3 + 2], cx, cy, cz);
            bool v = __float_as_uint(d) <= r2b;
            unsigned long long mk = __ballot(v);
            if (v) out[basep + __popcll(mk & lml)] = p;
            basep += __popcll(mk);
        }
        if (lane >= cnt) out[lane] = -1;
    } else if (cnt <= CAP) {
        // ---- pass 2: compact candidates (d2bits, idx) to LDS ----
        int basep = 0;
        #pragma unroll 8
        for (int j = 0; j < CH; ++j) {
            int p = j * 64 + lane;
            float d = d2_exact(pb[p * 3 + 0], pb[p * 3 + 1], pb[p * 3 + 2], cx, cy, cz);
            unsigned ubj = __float_as_uint(d);
            bool v = ubj <= r2b;
            unsigned long long mk = __ballot(v);
            if (v) buf[basep + __popcll(mk & lml)] = make_uint2(ubj, (unsigned)p);
            basep += __popcll(mk);
        }
        const int C2 = (cnt + 63) >> 6;   // wave-uniform
        unsigned cb[CAP / 64], ci[CAP / 64];
        #pragma unroll
        for (int e = 0; e < CAP / 64; ++e) {
            if (e >= C2) break;
            int p = e * 64 + lane;
            uint2 v = buf[p];
            cb[e] = (p < cnt) ? v.x : 0xFFFFFFFFu;
            ci[e] = v.y;
        }
        unsigned lo = 0, hi = r2b;
        while (lo < hi) {
            unsigned mid = lo + ((hi - lo) >> 1);
            int c = 0;
            #pragma unroll
            for (int e = 0; e < CAP / 64; ++e) {
                if (e >= C2) break;
                c += __popcll(__ballot(cb[e] <= mid));
            }
            if (c >= Kn) hi = mid; else lo = mid + 1;
        }
        const unsigned tt = lo;
        int cntLess = 0;
        #pragma unroll
        for (int e = 0; e < CAP / 64; ++e) {
            if (e >= C2) break;
            cntLess += __popcll(__ballot(cb[e] < tt));
        }
        const int quota = Kn - cntLess;
        int baseLt = 0, eqseen = 0;
        #pragma unroll
        for (int e = 0; e < CAP / 64; ++e) {
            if (e >= C2) break;
            bool lt = cb[e] < tt;
            bool eq = cb[e] == tt;
            unsigned long long mlt = __ballot(lt);
            unsigned long long meq = __ballot(eq);
            if (lt) out[baseLt + __popcll(mlt & lml)] = (int)ci[e];
            if (eq) {
                int rr = eqseen + __popcll(meq & lml);
                if (rr < quota) out[cntLess + rr] = (int)ci[e];
            }
            baseLt += __popcll(mlt);
            eqseen += __popcll(meq);
        }
    } else {
        // ---- fallback (cnt > CAP): recompute per pass; exact, never hot ----
        unsigned lo = 0, hi = r2b;
        while (lo < hi) {
            unsigned mid = lo + ((hi - lo) >> 1);
            int c = 0;
            for (int j = 0; j < CH; ++j) {
                int p = j * 64 + lane;
                float d = d2_exact(pb[p * 3 + 0], pb[p * 3 + 1], pb[p * 3 + 2], cx, cy, cz);
                c += __popcll(__ballot(__float_as_uint(d) <= mid));
            }
            if (c >= Kn) hi = mid; else lo = mid + 1;
        }
        const unsigned tt = lo;
        int cntLess = 0;
        for (int j = 0; j < CH; ++j) {
            int p = j * 64 + lane;
            float d = d2_exact(pb[p * 3 + 0], pb[p * 3 + 1], pb[p * 3 + 2], cx, cy, cz);
            cntLess += __popcll(__ballot(__float_as_uint(d) < tt));
        }
        const int quota = Kn - cntLess;
        int baseLt = 0, eqseen = 0;
        for (int j = 0; j < CH; ++j) {
            int p = j * 64 + lane;
            float d = d2_exact(pb[p * 3 + 0], pb[p * 3 + 1], pb[p * 3 + 2], cx, cy, cz);
            unsigned ubj = __float_as_uint(d);
            bool lt = ubj < tt;
            bool eq = ubj == tt;
            unsigned long long mlt = __ballot(lt);
            unsigned long long meq = __ballot(eq);
            if (lt) out[baseLt + __popcll(mlt & lml)] = p;
            if (eq) {
                int rr = eqseen + __popcll(meq & lml);
                if (rr < quota) out[cntLess + rr] = p;
            }
            baseLt += __popcll(mlt);
            eqseen += __popcll(meq);
        }
    }
}

// ---------------------------------------------------------------------------
// MLP1 core (wave, one center): 3 -> 64 relu -> 64 relu, masked max.
// ---------------------------------------------------------------------------
DEVINL void mlp1_core(const float* __restrict__ pb, float cx, float cy, float cz,
                      const int* nbrL, const float* __restrict__ w1aT,
                      const float* __restrict__ w1bT, const float* __restrict__ b1b,
                      float* __restrict__ orow, int lane) {
    const int ii = nbrL[lane];
    const bool valid = ii >= 0;
    const int i2 = valid ? ii : 0;
    const float* pp = pb + (size_t)i2 * 3;
    float rx = pp[0] - cx, ry = pp[1] - cy, rz = pp[2] - cz;
    float h1[64];
    #pragma unroll
    for (int h = 0; h < 64; ++h) {
        float4 wv = ((const float4*)w1aT)[h];
        float a = fmaf(rx, wv.x, fmaf(ry, wv.y, fmaf(rz, wv.z, wv.w)));
        h1[h] = fmaxf(a, 0.0f);
    }
    for (int c4 = 0; c4 < 16; ++c4) {
        float v4[4];
        #pragma unroll
        for (int cq = 0; cq < 4; ++cq) {
            int c = c4 * 4 + cq;
            float acc = b1b[c];
            const float4* wr = (const float4*)(w1bT + (size_t)c * 64);
            #pragma unroll
            for (int q = 0; q < 16; ++q) {
                float4 wv = wr[q];
                acc = fmaf(h1[4 * q + 0], wv.x, acc);
                acc = fmaf(h1[4 * q + 1], wv.y, acc);
                acc = fmaf(h1[4 * q + 2], wv.z, acc);
                acc = fmaf(h1[4 * q + 3], wv.w, acc);
            }
            float v = fmaxf(acc, 0.0f);
            v = valid ? v : -__builtin_inff();
            #pragma unroll
            for (int o = 32; o > 0; o >>= 1) v = fmaxf(v, __shfl_xor(v, o, 64));
            v4[cq] = v;
        }
        if (lane == 0)
            ((float4*)orow)[c4] = make_float4(v4[0], v4[1], v4[2], v4[3]);
    }
}

// ---------------------------------------------------------------------------
// MLP2 core (wave, one center): [x1(64)|relpos(3)] -> 128 relu -> 128 relu,
// masked max; writes X row cols 0..127.
// ---------------------------------------------------------------------------
DEVINL void mlp2_core(const float* __restrict__ x1b, const float* __restrict__ c1b,
                      float cx, float cy, float cz, const int* nbrL,
                      const float* __restrict__ w2aT, const float* __restrict__ w2bT,
                      const float* __restrict__ b2b, float* __restrict__ orow,
                      int lane) {
    const int ii = nbrL[lane];
    const bool valid = ii >= 0;
    const int i2 = valid ? ii : 0;

    float x[68];
    const float4* xr = (const float4*)(x1b + (size_t)i2 * 64);
    #pragma unroll
    for (int q = 0; q < 16; ++q) {
        float4 v = xr[q];
        x[4 * q + 0] = v.x; x[4 * q + 1] = v.y;
        x[4 * q + 2] = v.z; x[4 * q + 3] = v.w;
    }
    const float* cp = c1b + (size_t)i2 * 3;
    x[64] = cp[0] - cx;
    x[65] = cp[1] - cy;
    x[66] = cp[2] - cz;
    x[67] = 0.0f;

    float h1[128];
    #pragma unroll
    for (int h = 0; h < 128; ++h) {
        const float4* r4 = (const float4*)(w2aT + (size_t)h * 80);
        float acc = 0.0f;
        #pragma unroll
        for (int q = 0; q < 16; ++q) {
            float4 wv = r4[q];
            acc = fmaf(x[4 * q + 0], wv.x, acc);
            acc = fmaf(x[4 * q + 1], wv.y, acc);
            acc = fmaf(x[4 * q + 2], wv.z, acc);
            acc = fmaf(x[4 * q + 3], wv.w, acc);
        }
        float4 tl = r4[16];   // w64, w65, w66, bias
        acc = fmaf(x[64], tl.x, acc);
        acc = fmaf(x[65], tl.y, acc);
        acc = fmaf(x[66], tl.z, acc);
        acc += tl.w;
        h1[h] = fmaxf(acc, 0.0f);
    }
    for (int c4 = 0; c4 < 32; ++c4) {
        float v4[4];
        #pragma unroll
        for (int cq = 0; cq < 4; ++cq) {
            int c = c4 * 4 + cq;
            float acc = b2b[c];
            const float4* wr = (const float4*)(w2bT + (size_t)c * 128);
            #pragma unroll
            for (int q = 0; q < 32; ++q) {
                float4 wv = wr[q];
                acc = fmaf(h1[4 * q + 0], wv.x, acc);
                acc = fmaf(h1[4 * q + 1], wv.y, acc);
                acc = fmaf(h1[4 * q + 2], wv.z, acc);
                acc = fmaf(h1[4 * q + 3], wv.w, acc);
            }
            float v = fmaxf(acc, 0.0f);
            v = valid ? v : -__builtin_inff();
            #pragma unroll
            for (int o = 32; o > 0; o >>= 1) v = fmaxf(v, __shfl_xor(v, o, 64));
            v4[cq] = v;
        }
        if (lane == 0) {
            orow[c4 * 4 + 0] = v4[0]; orow[c4 * 4 + 1] = v4[1];
            orow[c4 * 4 + 2] = v4[2]; orow[c4 * 4 + 3] = v4[3];
        }
    }
}

// ---------------------------------------------------------------------------
// stage_kernel: 512 threads, LDS 94720 -> 1 block/CU = 2 waves/SIMD.
// amdgpu_waves_per_eu(2,2) pins the allocator's occupancy target to the
// LDS-forced 2 waves/EU -> VGPR budget 256, no scratch spill (R17 fix).
//  fps_stage: 1 = fps1 chunk (blocks 0..7), 2 = fps2 chunk, 0 = none.
//  w_stage:   1 = weight prep, 2 = workers1 (bq1+mlp1), 3 = workers2
//             (bq2+mlp2), 0 = none. Worker blocks follow the fps blocks.
//  Workers handle centers [w_begin, w_begin + (1<<wsh)) for all 8 clouds.
//  All inter-role dependencies are across LAUNCHES (stream-ordered).
// ---------------------------------------------------------------------------
__global__ __launch_bounds__(512)
__attribute__((amdgpu_waves_per_eu(2, 2)))
void stage_kernel(int fps_stage, int s_begin, int s_end,
                  int w_stage, int w_begin, int wsh,
                  const float* __restrict__ pos, float* __restrict__ c1,
                  float* __restrict__ c2, float* __restrict__ X,
                  float* __restrict__ x1,
                  float4* __restrict__ scp1_g, float* __restrict__ mind1_g,
                  float4* __restrict__ scp2_g, float* __restrict__ mind2_g,
                  const float* __restrict__ w1a, const float* __restrict__ b1a,
                  const float* __restrict__ w1b, const float* __restrict__ w2a,
                  const float* __restrict__ b2a, const float* __restrict__ w2b,
                  float* __restrict__ w1aT, float* __restrict__ w1bT,
                  float* __restrict__ w2aT, float* __restrict__ w2bT,
                  const float* __restrict__ b1b, const float* __restrict__ b2b) {
    __shared__ __align__(16) char smem[94720];
    const int t = threadIdx.x;
    const int lane = t & 63;
    const int wid = t >> 6;

    if (fps_stage > 0 && blockIdx.x < Bc) {
        const int b = blockIdx.x;
        float* journal = (float*)(smem + 69664);
        if (fps_stage == 1) {
            fps_chunk_body<Np, 8>(pos + (size_t)b * Np * 3, scp1_g + (size_t)b * Np,
                                  mind1_g + (size_t)b * Np, smem, t, lane,
                                  s_begin, s_end);
            int n = (s_end - s_begin) * 3;
            for (int i = t; i < n; i += 512)
                c1[(size_t)b * M1 * 3 + s_begin * 3 + i] = journal[i];
        } else {
            fps_chunk_body<M1, 4>(c1 + (size_t)b * M1 * 3, scp2_g + (size_t)b * M1,
                                  mind2_g + (size_t)b * M1, smem, t, lane,
                                  s_begin, s_end);
            int n = (s_end - s_begin) * 3;
            for (int i = t; i < n; i += 512)
                c2[(size_t)b * M2 * 3 + s_begin * 3 + i] = journal[i];
            for (int i = t; i < n; i += 512) {
                int s = i / 3, k = i - s * 3;
                X[(size_t)(b * M2 + s_begin + s) * LDX + 128 + k] = journal[i];
            }
        }
        return;
    }

    const int wb = (fps_stage > 0) ? (int)blockIdx.x - Bc : (int)blockIdx.x;
    const int nw = (fps_stage > 0) ? (int)gridDim.x - Bc : (int)gridDim.x;

    if (w_stage == 1) {
        // ---------------- weight-transpose prep ----------------
        int i = wb * 512 + t;  // 0..16383
        if (i < 64 * 4) {
            int h = i >> 2, d = i & 3;
            w1aT[i] = (d < 3) ? w1a[d * 64 + h] : b1a[h];
        }
        if (i < 64 * 64) {
            int c = i >> 6, h = i & 63;
            w1bT[i] = w1b[h * 64 + c];
        }
        if (i < 128 * 80) {
            int h = i / 80, d = i - h * 80;
            w2aT[i] = (d < 67) ? w2a[d * 128 + h] : ((d == 67) ? b2a[h] : 0.0f);
        }
        if (i < 128 * 128) {
            int c = i >> 7, h = i & 127;
            w2bT[i] = w2b[h * 128 + c];
        }
        return;
    }

    if (w_stage == 2) {
        // ---------------- workers1: fused bq1 + mlp1 ----------------
        uint2* cbuf = (uint2*)smem + (size_t)wid * 1024;       // 8 KB/wave
        int* nbrL = (int*)(smem + 65536) + wid * 64;
        const int span_mask = (1 << wsh) - 1;
        const int ntasks = Bc << wsh;
        for (int task = wb * 8 + wid; task < ntasks; task += nw * 8) {
            const int b = task >> wsh;
            const int s = w_begin + (task & span_mask);
            const int w = b * M1 + s;
            const float* cr = c1 + (size_t)w * 3;
            float cx = cr[0], cy = cr[1], cz = cr[2];
            const float* pb = pos + (size_t)b * Np * 3;
            bq_core<Np>(pb, cx, cy, cz, (float)(0.2 * 0.2), nbrL, cbuf, lane);
            mlp1_core(pb, cx, cy, cz, nbrL, w1aT, w1bT, b1b,
                      x1 + (size_t)w * 64, lane);
        }
        return;
    }

    if (w_stage == 3) {
        // ---------------- workers2: fused bq2 + mlp2 ----------------
        uint2* cbuf = (uint2*)smem + (size_t)wid * 1024;
        int* nbrL = (int*)(smem + 65536) + wid * 64;
        const int span_mask = (1 << wsh) - 1;
        const int ntasks = Bc << wsh;
        for (int task = wb * 8 + wid; task < ntasks; task += nw * 8) {
            const int b = task >> wsh;
            const int s = w_begin + (task & span_mask);
            const int w = b * M2 + s;
            const float* cr = c2 + (size_t)w * 3;
            float cx = cr[0], cy = cr[1], cz = cr[2];
            const float* c1b = c1 + (size_t)b * M1 * 3;
            bq_core<M1>(c1b, cx, cy, cz, (float)(0.4 * 0.4), nbrL, cbuf, lane);
            mlp2_core(x1 + (size_t)b * M1 * 64, c1b, cx, cy, cz, nbrL,
                      w2aT, w2bT, b2b, X + (size_t)w * LDX, lane);
        }
        return;
    }
}

// ---------------------------------------------------------------------------
// GEMM1: H[r][c] = relu(b3a[c] + sum_i X[r][i] * w3a[i][c]), K=131.
// ---------------------------------------------------------------------------
__global__ __launch_bounds__(256)
void gemm1_kernel(const float* __restrict__ X, const float* __restrict__ w3a,
                  const float* __restrict__ b3a, float* __restrict__ H) {
    const int r = blockIdx.x;
    const int c = threadIdx.x;
    const float* xr = X + (size_t)r * LDX;
    float acc = b3a[c];
    for (int i = 0; i < 131; ++i)
        acc = fmaf(xr[i], w3a[(size_t)i * 256 + c], acc);
    H[(size_t)r * 256 + c] = fmaxf(acc, 0.0f);
}

// ---------------------------------------------------------------------------
// GEMM2 fused with per-tile row max: 32x64 tile, BK=32.
// ---------------------------------------------------------------------------
__global__ __launch_bounds__(256)
void gemm2_kernel(const float* __restrict__ H, const float* __restrict__ w3b,
                  float* __restrict__ part) {
    __shared__ float As[32][33];
    __shared__ float Bs[32][64];
    __shared__ float red[8][64];
    const int bidx = blockIdx.x;
    const int nt = bidx & 15;
    const int mt = (bidx >> 4) & 15;
    const int b = bidx >> 8;
    const int row0 = b * M2 + mt * 32;
    const int col0 = nt * 64;
    const int t = threadIdx.x;
    const int rg = t >> 5, cg = t & 31;

    float acc[4][2] = {{0.f, 0.f}, {0.f, 0.f}, {0.f, 0.f}, {0.f, 0.f}};
    for (int k0 = 0; k0 < 256; k0 += 32) {
        #pragma unroll
        for (int q = 0; q < 4; ++q) {
            int id = t + q * 256;
            As[id >> 5][id & 31] = H[(size_t)(row0 + (id >> 5)) * 256 + k0 + (id & 31)];
        }
        #pragma unroll
        for (int q = 0; q < 8; ++q) {
            int id = t + q * 256;
            Bs[id >> 6][id & 63] = w3b[(size_t)(k0 + (id >> 6)) * 1024 + col0 + (id & 63)];
        }
        __syncthreads();
        #pragma unroll
        for (int kk = 0; kk < 32; ++kk) {
            float b0 = Bs[kk][cg * 2 + 0];
            float b1 = Bs[kk][cg * 2 + 1];
            #pragma unroll
            for (int j = 0; j < 4; ++j) {
                float a = As[rg * 4 + j][kk];
                acc[j][0] = fmaf(a, b0, acc[j][0]);
                acc[j][1] = fmaf(a, b1, acc[j][1]);
            }
        }
        __syncthreads();
    }
    float m0 = fmaxf(fmaxf(acc[0][0], acc[1][0]), fmaxf(acc[2][0], acc[3][0]));
    float m1 = fmaxf(fmaxf(acc[0][1], acc[1][1]), fmaxf(acc[2][1], acc[3][1]));
    red[rg][cg * 2 + 0] = m0;
    red[rg][cg * 2 + 1] = m1;
    __syncthreads();
    if (t < 64) {
        float v = red[0][t];
        #pragma unroll
        for (int q = 1; q < 8; ++q) v = fmaxf(v, red[q][t]);
        part[((size_t)b * 16 + mt) * 1024 + col0 + t] = v;
    }
}

// ---------------------------------------------------------------------------
// Final max over the 16 m-tiles per cloud + bias.
// ---------------------------------------------------------------------------
__global__ __launch_bounds__(256)
void rmax_kernel(const float* __restrict__ part, const float* __restrict__ b3b,
                 float* __restrict__ out) {
    int i = blockIdx.x * 256 + threadIdx.x;  // 8192 = B*1024
    int b = i >> 10, c = i & 1023;
    float v = -__builtin_inff();
    #pragma unroll
    for (int tt = 0; tt < 16; ++tt)
        v = fmaxf(v, part[((size_t)b * 16 + tt) * 1024 + c]);
    out[i] = v + b3b[c];
}

// ---------------------------------------------------------------------------
extern "C" void kernel_launch(void* const* d_in, const int* in_sizes, int n_in,
                              void* d_out, int out_size, void* d_ws, size_t ws_size,
                              hipStream_t stream) {
    const float* pos = (const float*)d_in[0];
    const float* w1a = (const float*)d_in[1];
    const float* b1a = (const float*)d_in[2];
    const float* w1b = (const float*)d_in[3];
    const float* b1b = (const float*)d_in[4];
    const float* w2a = (const float*)d_in[5];
    const float* b2a = (const float*)d_in[6];
    const float* w2b = (const float*)d_in[7];
    const float* b2b = (const float*)d_in[8];
    const float* w3a = (const float*)d_in[9];
    const float* b3a = (const float*)d_in[10];
    const float* w3b = (const float*)d_in[11];
    const float* b3b = (const float*)d_in[12];
    float* out = (float*)d_out;

    char* ws = (char*)d_ws;
    size_t off = 0;
    auto alloc = [&](size_t bytes) -> char* {
        char* p = ws + off;
        off += (bytes + 255) & ~(size_t)255;
        return p;
    };
    float*  c1     = (float*)alloc(sizeof(float) * Bc * M1 * 3);
    float*  c2     = (float*)alloc(sizeof(float) * Bc * M2 * 3);
    float*  x1     = (float*)alloc(sizeof(float) * Bc * M1 * 64);
    float*  X      = (float*)alloc(sizeof(float) * Bc * M2 * LDX);
    float*  H      = (float*)alloc(sizeof(float) * Bc * M2 * 256);
    float*  part   = (float*)alloc(sizeof(float) * Bc * 16 * 1024);
    float*  w1aT   = (float*)alloc(sizeof(float) * 64 * 4);
    float*  w1bT   = (float*)alloc(sizeof(float) * 64 * 64);
    float*  w2aT   = (float*)alloc(sizeof(float) * 128 * 80);
    float*  w2bT   = (float*)alloc(sizeof(float) * 128 * 128);
    float4* scp1_g = (float4*)alloc(sizeof(float4) * Bc * Np);
    float*  mind1g = (float*)alloc(sizeof(float) * Bc * Np);
    float4* scp2_g = (float4*)alloc(sizeof(float4) * Bc * M1);
    float*  mind2g = (float*)alloc(sizeof(float) * Bc * M1);

    auto launch = [&](int grid, int fs, int sb, int se, int wsg, int wbg, int wsh) {
        stage_kernel<<<dim3(grid), dim3(512), 0, stream>>>(
            fs, sb, se, wsg, wbg, wsh,
            pos, c1, c2, X, x1, scp1_g, mind1g, scp2_g, mind2g,
            w1a, b1a, w1b, w2a, b2a, w2b, w1aT, w1bT, w2aT, w2bT, b1b, b2b);
    };

    // LA: fps1 chunk [0,512) + weight prep
    launch(Bc + 32, 1, 0, 512, 1, 0, 0);
    // LB1..3: fps1 chunks + workers1 for the previous chunk (span 512)
    launch(Bc + 240, 1, 512, 1024, 2, 0, 9);
    launch(Bc + 240, 1, 1024, 1536, 2, 512, 9);
    launch(Bc + 240, 1, 1536, 2048, 2, 1024, 9);
    // LC: fps2 chunk [0,256) + workers1 for fps1 chunk 3 (span 512)
    launch(Bc + 240, 2, 0, 256, 2, 1536, 9);
    // LD: fps2 chunk [256,512) + workers2 for fps2 chunk 0 (span 256)
    launch(Bc + 240, 2, 256, 512, 3, 0, 8);
    // LE: workers2 for fps2 chunk 1 (span 256)
    launch(240, 0, 0, 0, 3, 256, 8);

    gemm1_kernel<<<dim3(Bc * M2), dim3(256), 0, stream>>>(X, w3a, b3a, H);
    gemm2_kernel<<<dim3(Bc * 16 * 16), dim3(256), 0, stream>>>(H, w3b, part);
    rmax_kernel<<<dim3(32), dim3(256), 0, stream>>>(part, b3b, out);
}

// Round 10
// 2439.523 us; speedup vs baseline: 1.3968x; 1.1137x over previous
//
#include <hip/hip_runtime.h>
#include <cstdint>
#include <cstddef>

// ---------------------------------------------------------------------------
// PointNet++ (B=8, N=4096, K=64, N1=2048, N2=512, r1=0.2, r2=0.4), fp32.
// Selection stages (FPS argmax, ball-query top-k) use __f*_rn intrinsics in
// numpy's association order -> selected index sets match bit-exactly.
// R19: identical to R18 (bench infra failed twice; resubmitting).
// R18: evict the MLPs from the merged stage kernel. R17 evidence: the
// conflict-free 593us dispatch = workers-only launch -> WORKERS are the
// 593us, caused by mlp spill (mlp2 needs ~200 regs, kernel got 116) at
// 1 block/CU where nothing hides scratch latency. Fix: mixed launches run
// bq-ONLY workers (two-pass bq, ~60 regs, writes global nbr1/nbr2 as in
// R13); mlp1/mlp2 revert to R13's standalone kernels (own regalloc, high
// occupancy -- proven fast). Every component here has previously passed.
// R15: chunked-FPS overlap, stream-ordered deps only. fps1 = 4 chunks of
// 512 selections, fps2 = 2 chunks of 256; each launch = 8 fps-chunk blocks
// + 240 bq-worker blocks for the PREVIOUS chunk's centers.
// Chunk state: sorted scp (float4) persisted once; per-thread mind[] saved
// per chunk; candidate key recomputed at chunk start (bit-exact invariant).
// R13: R9 combine (slots[3] + lane63 atomicMax + u64 DPP); float4-packed
// sorted coords+key so the dependent coord lookup is one ds_read_b128.
// R5 core: exact lazy pruning; Morton-bucket-sorted points; per-thread bbox
// lower bound skips the recompute when it cannot change any mind[j].
// Key = (d2bits<<24)|((~orig&0xFFF)<<12)|sortedpos.
// ---------------------------------------------------------------------------

static constexpr int Bc = 8;     // batch (clouds)
static constexpr int Np = 4096;  // points per cloud
static constexpr int Kn = 64;    // max neighbors
static constexpr int M1 = 2048;  // SA1 centers
static constexpr int M2 = 512;   // SA2 centers
static constexpr int LDX = 132;  // row stride of X = [x2 (128) | c2 (3) | pad]

#define DEVINL __device__ __forceinline__

// exact replication of np: ((dx*dx + dy*dy) + dz*dz), no fma contraction
DEVINL float d2_exact(float ax, float ay, float az, float bx, float by, float bz) {
    float dx = __fsub_rn(ax, bx);
    float dy = __fsub_rn(ay, by);
    float dz = __fsub_rn(az, bz);
    float xx = __fmul_rn(dx, dx);
    float yy = __fmul_rn(dy, dy);
    float zz = __fmul_rn(dz, dz);
    return __fadd_rn(__fadd_rn(xx, yy), zz);
}

template <int CTRL, int RM, int BM>
DEVINL unsigned long long dpp_max_step(unsigned long long k) {
    unsigned lo = (unsigned)k, hi = (unsigned)(k >> 32);
    unsigned slo = (unsigned)__builtin_amdgcn_update_dpp(0, (int)lo, CTRL, RM, BM, true);
    unsigned shi = (unsigned)__builtin_amdgcn_update_dpp(0, (int)hi, CTRL, RM, BM, true);
    unsigned long long s = ((unsigned long long)shi << 32) | (unsigned long long)slo;
    return s > k ? s : k;
}

DEVINL unsigned long long wave_max_u64_dpp(unsigned long long k) {
    k = dpp_max_step<0x111, 0xf, 0xf>(k);  // row_shr:1
    k = dpp_max_step<0x112, 0xf, 0xf>(k);  // row_shr:2
    k = dpp_max_step<0x114, 0xf, 0xf>(k);  // row_shr:4
    k = dpp_max_step<0x118, 0xf, 0xf>(k);  // row_shr:8
    k = dpp_max_step<0x142, 0xa, 0xf>(k);  // row_bcast:15
    k = dpp_max_step<0x143, 0xc, 0xf>(k);  // row_bcast:31 -> lane 63 = wave max
    return k;
}

DEVINL unsigned mort3(unsigned v) {  // 3 bits -> bits 0,3,6
    return (v & 1u) | ((v & 2u) << 2) | ((v & 4u) << 4);
}

DEVINL unsigned cell_of(float x, float y, float z) {
    int ix = (int)(x * 8.0f); ix = ix < 0 ? 0 : (ix > 7 ? 7 : ix);
    int iy = (int)(y * 8.0f); iy = iy < 0 ? 0 : (iy > 7 ? 7 : iy);
    int iz = (int)(z * 8.0f); iz = iz < 0 ? 0 : (iz > 7 ? 7 : iz);
    return mort3((unsigned)ix) | (mort3((unsigned)iy) << 1) | (mort3((unsigned)iz) << 2);
}

// inclusive Hillis-Steele scan over 512 entries, 512 threads. 9 barriers.
DEVINL unsigned* scan512(unsigned* h0, unsigned* h1, int t) {
    unsigned* src = h0; unsigned* dst = h1;
    for (int d = 1; d < 512; d <<= 1) {
        unsigned v = src[t];
        if (t >= d) v += src[t - d];
        dst[t] = v;
        __syncthreads();
        unsigned* tmp = src; src = dst; dst = tmp;
    }
    return src;
}

// ---------------------------------------------------------------------------
// FPS chunk: selections [s_begin, s_end) for one cloud. 512 threads.
// NPTS points, PT = NPTS/512 per thread. State in scp_g (sorted, persisted at
// chunk 0) and mind_g (per-thread min distances, saved every chunk).
// Journal (LDS) holds the chunk's selected coords for the caller to flush.
// ---------------------------------------------------------------------------
template <int NPTS, int PT>
DEVINL void fps_chunk_body(const float* __restrict__ srcpts,
                           float4* __restrict__ scp_g,
                           float* __restrict__ mind_g,
                           char* smem, int t, int lane,
                           int s_begin, int s_end) {
    constexpr int NT = NPTS / PT;   // 512
    float4* scp = (float4*)smem;
    unsigned* h0 = (unsigned*)(smem + 65536);
    unsigned* h1 = (unsigned*)(smem + 67584);
    unsigned long long* slots = (unsigned long long*)(smem + 69632);
    float* journal = (float*)(smem + 69664);

    float px[PT], py[PT], pz[PT], mind[PT];
    unsigned oi[PT];
    unsigned long long ck = 0;

    if (s_begin == 0) {
        // -------- chunk 0: load, Morton-bucket sort, persist, seed --------
        float gx[PT], gy[PT], gz[PT];
        unsigned gc[PT];
        #pragma unroll
        for (int j = 0; j < PT; ++j) {
            int p = j * NT + t;
            gx[j] = srcpts[p * 3 + 0];
            gy[j] = srcpts[p * 3 + 1];
            gz[j] = srcpts[p * 3 + 2];
            gc[j] = cell_of(gx[j], gy[j], gz[j]);
        }
        float x0 = srcpts[0], y0 = srcpts[1], z0 = srcpts[2];
        h0[t] = 0;
        if (t == 0) { slots[0] = 0; slots[1] = 0; slots[2] = 0; }
        __syncthreads();
        #pragma unroll
        for (int j = 0; j < PT; ++j) atomicAdd(&h0[gc[j]], 1u);
        __syncthreads();
        unsigned cnt = h0[t];
        unsigned* inc = scan512(h0, h1, t);
        inc[t] -= cnt;
        __syncthreads();
        #pragma unroll
        for (int j = 0; j < PT; ++j) {
            unsigned p = atomicAdd(&inc[gc[j]], 1u);
            unsigned key = ((0xFFFu - (unsigned)(j * NT + t)) << 12) | p;
            scp[p] = make_float4(gx[j], gy[j], gz[j], __uint_as_float(key));
        }
        __syncthreads();
        for (int k = t; k < NPTS; k += NT) scp_g[k] = scp[k];  // persist sort
        #pragma unroll
        for (int j = 0; j < PT; ++j) {
            float4 v = scp[t * PT + j];
            px[j] = v.x; py[j] = v.y; pz[j] = v.z;
            oi[j] = __float_as_uint(v.w);
        }
        #pragma unroll
        for (int j = 0; j < PT; ++j) {
            float d = d2_exact(px[j], py[j], pz[j], x0, y0, z0);
            mind[j] = d;
            unsigned long long kj =
                ((unsigned long long)__float_as_uint(d) << 24) | (unsigned long long)oi[j];
            if (kj > ck) ck = kj;
        }
        if (t == 0) { journal[0] = x0; journal[1] = y0; journal[2] = z0; }
    } else {
        // -------- chunk >0: restore state (bit-exact recompute of ck) -----
        if (t == 0) { slots[0] = 0; slots[1] = 0; slots[2] = 0; }
        for (int k = t; k < NPTS; k += NT) scp[k] = scp_g[k];
        __syncthreads();
        #pragma unroll
        for (int j = 0; j < PT; ++j) {
            float4 v = scp[t * PT + j];
            px[j] = v.x; py[j] = v.y; pz[j] = v.z;
            oi[j] = __float_as_uint(v.w);
        }
        #pragma unroll
        for (int j = 0; j < PT; ++j) mind[j] = mind_g[t * PT + j];
        #pragma unroll
        for (int j = 0; j < PT; ++j) {
            unsigned long long kj =
                ((unsigned long long)__float_as_uint(mind[j]) << 24) |
                (unsigned long long)oi[j];
            if (kj > ck) ck = kj;
        }
    }

    float lox = px[0], hix = px[0], loy = py[0], hiy = py[0], loz = pz[0], hiz = pz[0];
    #pragma unroll
    for (int j = 1; j < PT; ++j) {
        lox = fminf(lox, px[j]); hix = fmaxf(hix, px[j]);
        loy = fminf(loy, py[j]); hiy = fmaxf(hiy, py[j]);
        loz = fminf(loz, pz[j]); hiz = fmaxf(hiz, pz[j]);
    }

    float bmax = __uint_as_float((unsigned)(ck >> 24));
    unsigned long long wkey = wave_max_u64_dpp(ck);
    if (lane == 63) atomicMax(&slots[1], wkey);

    int rd = 1, wr = 2, rs = 0;
    for (int s = (s_begin == 0 ? 1 : s_begin); s < s_end; ++s) {
        __syncthreads();
        unsigned long long km = slots[rd];
        if (t == 0) slots[rs] = 0;
        unsigned spos = (unsigned)km & 0xFFFu;
        float4 cc = scp[spos];
        float cx = cc.x, cy = cc.y, cz = cc.z;
        if (t == 0) {
            int jj = (s - s_begin) * 3;
            journal[jj + 0] = cx; journal[jj + 1] = cy; journal[jj + 2] = cz;
        }
        float dxv = fmaxf(fmaxf(lox - cx, cx - hix), 0.0f);
        float dyv = fmaxf(fmaxf(loy - cy, cy - hiy), 0.0f);
        float dzv = fmaxf(fmaxf(loz - cz, cz - hiz), 0.0f);
        float L = dxv * dxv + dyv * dyv + dzv * dzv;
        bool fire = (L * 0.999f <= bmax);
        if (fire) {
            unsigned long long nck = 0;
            #pragma unroll
            for (int j = 0; j < PT; ++j) {
                float d = d2_exact(px[j], py[j], pz[j], cx, cy, cz);
                float m = fminf(mind[j], d);
                mind[j] = m;
                unsigned long long kj =
                    ((unsigned long long)__float_as_uint(m) << 24) | (unsigned long long)oi[j];
                if (kj > nck) nck = kj;
            }
            ck = nck;
            bmax = __uint_as_float((unsigned)(ck >> 24));
        }
        if (__ballot(fire) != 0ull) wkey = wave_max_u64_dpp(ck);
        if (lane == 63) atomicMax(&slots[wr], wkey);
        int nrd = wr; wr = rs; rs = rd; rd = nrd;
    }
    __syncthreads();   // journal complete; mind final
    #pragma unroll
    for (int j = 0; j < PT; ++j) mind_g[t * PT + j] = mind[j];
}

// ---------------------------------------------------------------------------
// Ball-query core (two-pass, no persistent ub[] -- R17-verified): pass 1
// counts; pass 2 RECOMPUTES d2_exact (pure -> bit-identical) and emits. >K
// in radius -> compact to LDS buf + exact kth-smallest binary search. Ties
// by smallest index (== lax.top_k). out = GLOBAL nbr row; -1 pads.
// ---------------------------------------------------------------------------
template <int NPT>
DEVINL void bq_core(const float* __restrict__ pb, float cx, float cy, float cz,
                    float r2, int* out, uint2* buf, int lane) {
    constexpr int CH = NPT / 64;
    constexpr int CAP = 1024;
    const unsigned r2b = __float_as_uint(r2);
    const unsigned long long lml = (1ull << lane) - 1ull;

    // ---- pass 1: count in-radius points (no per-chunk state retained) ----
    int cnt = 0;
    #pragma unroll 8
    for (int j = 0; j < CH; ++j) {
        int p = j * 64 + lane;
        float d = d2_exact(pb[p * 3 + 0], pb[p * 3 + 1], pb[p * 3 + 2], cx, cy, cz);
        cnt += __popcll(__ballot(__float_as_uint(d) <= r2b));
    }

    if (cnt <= Kn) {
        // ---- pass 2: emit indices in index order ----
        int basep = 0;
        #pragma unroll 8
        for (int j = 0; j < CH; ++j) {
            int p = j * 64 + lane;
            float d = d2_exact(pb[p * 3 + 0], pb[p * 3 + 1], pb[p * 3 + 2], cx, cy, cz);
            bool v = __float_as_uint(d) <= r2b;
            unsigned long long mk = __ballot(v);
            if (v) out[basep + __popcll(mk & lml)] = p;
            basep += __popcll(mk);
        }
        if (lane >= cnt) out[lane] = -1;
    } else if (cnt <= CAP) {
        // ---- pass 2: compact candidates (d2bits, idx) to LDS ----
        int basep = 0;
        #pragma unroll 8
        for (int j = 0; j < CH; ++j) {
            int p = j * 64 + lane;
            float d = d2_exact(pb[p * 3 + 0], pb[p * 3 + 1], pb[p * 3 + 2], cx, cy, cz);
            unsigned ubj = __float_as_uint(d);
            bool v = ubj <= r2b;
            unsigned long long mk = __ballot(v);
            if (v) buf[basep + __popcll(mk & lml)] = make_uint2(ubj, (unsigned)p);
            basep += __popcll(mk);
        }
        const int C2 = (cnt + 63) >> 6;   // wave-uniform
        unsigned cb[CAP / 64], ci[CAP / 64];
        #pragma unroll
        for (int e = 0; e < CAP / 64; ++e) {
            if (e >= C2) break;
            int p = e * 64 + lane;
            uint2 v = buf[p];
            cb[e] = (p < cnt) ? v.x : 0xFFFFFFFFu;
            ci[e] = v.y;
        }
        unsigned lo = 0, hi = r2b;
        while (lo < hi) {
            unsigned mid = lo + ((hi - lo) >> 1);
            int c = 0;
            #pragma unroll
            for (int e = 0; e < CAP / 64; ++e) {
                if (e >= C2) break;
                c += __popcll(__ballot(cb[e] <= mid));
            }
            if (c >= Kn) hi = mid; else lo = mid + 1;
        }
        const unsigned tt = lo;
        int cntLess = 0;
        #pragma unroll
        for (int e = 0; e < CAP / 64; ++e) {
            if (e >= C2) break;
            cntLess += __popcll(__ballot(cb[e] < tt));
        }
        const int quota = Kn - cntLess;
        int baseLt = 0, eqseen = 0;
        #pragma unroll
        for (int e = 0; e < CAP / 64; ++e) {
            if (e >= C2) break;
            bool lt = cb[e] < tt;
            bool eq = cb[e] == tt;
            unsigned long long mlt = __ballot(lt);
            unsigned long long meq = __ballot(eq);
            if (lt) out[baseLt + __popcll(mlt & lml)] = (int)ci[e];
            if (eq) {
                int rr = eqseen + __popcll(meq & lml);
                if (rr < quota) out[cntLess + rr] = (int)ci[e];
            }
            baseLt += __popcll(mlt);
            eqseen += __popcll(meq);
        }
    } else {
        // ---- fallback (cnt > CAP): recompute per pass; exact, never hot ----
        unsigned lo = 0, hi = r2b;
        while (lo < hi) {
            unsigned mid = lo + ((hi - lo) >> 1);
            int c = 0;
            for (int j = 0; j < CH; ++j) {
                int p = j * 64 + lane;
                float d = d2_exact(pb[p * 3 + 0], pb[p * 3 + 1], pb[p * 3 + 2], cx, cy, cz);
                c += __popcll(__ballot(__float_as_uint(d) <= mid));
            }
            if (c >= Kn) hi = mid; else lo = mid + 1;
        }
        const unsigned tt = lo;
        int cntLess = 0;
        for (int j = 0; j < CH; ++j) {
            int p = j * 64 + lane;
            float d = d2_exact(pb[p * 3 + 0], pb[p * 3 + 1], pb[p * 3 + 2], cx, cy, cz);
            cntLess += __popcll(__ballot(__float_as_uint(d) < tt));
        }
        const int quota = Kn - cntLess;
        int baseLt = 0, eqseen = 0;
        for (int j = 0; j < CH; ++j) {
            int p = j * 64 + lane;
            float d = d2_exact(pb[p * 3 + 0], pb[p * 3 + 1], pb[p * 3 + 2], cx, cy, cz);
            unsigned ubj = __float_as_uint(d);
            bool lt = ubj < tt;
            bool eq = ubj == tt;
            unsigned long long mlt = __ballot(lt);
            unsigned long long meq = __ballot(eq);
            if (lt) out[baseLt + __popcll(mlt & lml)] = p;
            if (eq) {
                int rr = eqseen + __popcll(meq & lml);
                if (rr < quota) out[cntLess + rr] = p;
            }
            baseLt += __popcll(mlt);
            eqseen += __popcll(meq);
        }
    }
}

// ---------------------------------------------------------------------------
// stage_kernel: 512 threads, LDS 94720 -> 1 block/CU = 2 waves/SIMD
// (amdgpu_waves_per_eu(2,2) matches; no MLP code -> no spill anywhere).
//  fps_stage: 1 = fps1 chunk (blocks 0..7), 2 = fps2 chunk, 0 = none.
//  w_stage:   1 = weight prep, 2 = bq1 workers (-> global nbr1),
//             3 = bq2 workers (-> global nbr2), 0 = none.
//  Workers handle centers [w_begin, w_begin + (1<<wsh)) for all 8 clouds.
//  All inter-role dependencies are across LAUNCHES (stream-ordered).
// ---------------------------------------------------------------------------
__global__ __launch_bounds__(512)
__attribute__((amdgpu_waves_per_eu(2, 2)))
void stage_kernel(int fps_stage, int s_begin, int s_end,
                  int w_stage, int w_begin, int wsh,
                  const float* __restrict__ pos, float* __restrict__ c1,
                  float* __restrict__ c2, float* __restrict__ X,
                  int* __restrict__ nbr1, int* __restrict__ nbr2,
                  float4* __restrict__ scp1_g, float* __restrict__ mind1_g,
                  float4* __restrict__ scp2_g, float* __restrict__ mind2_g,
                  const float* __restrict__ w1a, const float* __restrict__ b1a,
                  const float* __restrict__ w1b, const float* __restrict__ w2a,
                  const float* __restrict__ b2a, const float* __restrict__ w2b,
                  float* __restrict__ w1aT, float* __restrict__ w1bT,
                  float* __restrict__ w2aT, float* __restrict__ w2bT) {
    __shared__ __align__(16) char smem[94720];
    const int t = threadIdx.x;
    const int lane = t & 63;
    const int wid = t >> 6;

    if (fps_stage > 0 && blockIdx.x < Bc) {
        const int b = blockIdx.x;
        float* journal = (float*)(smem + 69664);
        if (fps_stage == 1) {
            fps_chunk_body<Np, 8>(pos + (size_t)b * Np * 3, scp1_g + (size_t)b * Np,
                                  mind1_g + (size_t)b * Np, smem, t, lane,
                                  s_begin, s_end);
            int n = (s_end - s_begin) * 3;
            for (int i = t; i < n; i += 512)
                c1[(size_t)b * M1 * 3 + s_begin * 3 + i] = journal[i];
        } else {
            fps_chunk_body<M1, 4>(c1 + (size_t)b * M1 * 3, scp2_g + (size_t)b * M1,
                                  mind2_g + (size_t)b * M1, smem, t, lane,
                                  s_begin, s_end);
            int n = (s_end - s_begin) * 3;
            for (int i = t; i < n; i += 512)
                c2[(size_t)b * M2 * 3 + s_begin * 3 + i] = journal[i];
            for (int i = t; i < n; i += 512) {
                int s = i / 3, k = i - s * 3;
                X[(size_t)(b * M2 + s_begin + s) * LDX + 128 + k] = journal[i];
            }
        }
        return;
    }

    const int wb = (fps_stage > 0) ? (int)blockIdx.x - Bc : (int)blockIdx.x;
    const int nw = (fps_stage > 0) ? (int)gridDim.x - Bc : (int)gridDim.x;

    if (w_stage == 1) {
        // ---------------- weight-transpose prep ----------------
        int i = wb * 512 + t;  // 0..16383
        if (i < 64 * 4) {
            int h = i >> 2, d = i & 3;
            w1aT[i] = (d < 3) ? w1a[d * 64 + h] : b1a[h];
        }
        if (i < 64 * 64) {
            int c = i >> 6, h = i & 63;
            w1bT[i] = w1b[h * 64 + c];
        }
        if (i < 128 * 80) {
            int h = i / 80, d = i - h * 80;
            w2aT[i] = (d < 67) ? w2a[d * 128 + h] : ((d == 67) ? b2a[h] : 0.0f);
        }
        if (i < 128 * 128) {
            int c = i >> 7, h = i & 127;
            w2bT[i] = w2b[h * 128 + c];
        }
        return;
    }

    if (w_stage == 2) {
        // ---------------- bq1 workers -> global nbr1 ----------------
        uint2* cbuf = (uint2*)smem + (size_t)wid * 1024;       // 8 KB/wave
        const int span_mask = (1 << wsh) - 1;
        const int ntasks = Bc << wsh;
        for (int task = wb * 8 + wid; task < ntasks; task += nw * 8) {
            const int b = task >> wsh;
            const int s = w_begin + (task & span_mask);
            const int w = b * M1 + s;
            const float* cr = c1 + (size_t)w * 3;
            bq_core<Np>(pos + (size_t)b * Np * 3, cr[0], cr[1], cr[2],
                        (float)(0.2 * 0.2), nbr1 + (size_t)w * Kn, cbuf, lane);
        }
        return;
    }

    if (w_stage == 3) {
        // ---------------- bq2 workers -> global nbr2 ----------------
        uint2* cbuf = (uint2*)smem + (size_t)wid * 1024;
        const int span_mask = (1 << wsh) - 1;
        const int ntasks = Bc << wsh;
        for (int task = wb * 8 + wid; task < ntasks; task += nw * 8) {
            const int b = task >> wsh;
            const int s = w_begin + (task & span_mask);
            const int w = b * M2 + s;
            const float* cr = c2 + (size_t)w * 3;
            bq_core<M1>(c1 + (size_t)b * M1 * 3, cr[0], cr[1], cr[2],
                        (float)(0.4 * 0.4), nbr2 + (size_t)w * Kn, cbuf, lane);
        }
        return;
    }
}

// ---------------------------------------------------------------------------
// MLP1 (standalone, R13-proven): wave per center, lane per neighbor.
// 3 -> 64 relu -> 64 relu, masked max via shfl_xor reduce.
// ---------------------------------------------------------------------------
__global__ __launch_bounds__(256)
void mlp1_kernel(const float* __restrict__ pos, const float* __restrict__ c1,
                 const int* __restrict__ nbr, const float* __restrict__ w1aT,
                 const float* __restrict__ w1bT, const float* __restrict__ b1b,
                 float* __restrict__ x1) {
    const int lane = threadIdx.x & 63;
    int w = __builtin_amdgcn_readfirstlane((int)(blockIdx.x * 4 + (threadIdx.x >> 6)));
    const int b = w >> 11;
    const int ii = nbr[(size_t)w * Kn + lane];
    const bool valid = ii >= 0;
    const int i2 = valid ? ii : 0;
    const float* pp = pos + ((size_t)b * Np + i2) * 3;
    const float* cc = c1 + (size_t)w * 3;
    float rx = pp[0] - cc[0], ry = pp[1] - cc[1], rz = pp[2] - cc[2];
    float h1[64];
    #pragma unroll
    for (int h = 0; h < 64; ++h) {
        float4 wv = ((const float4*)w1aT)[h];
        float a = fmaf(rx, wv.x, fmaf(ry, wv.y, fmaf(rz, wv.z, wv.w)));
        h1[h] = fmaxf(a, 0.0f);
    }
    float* orow = x1 + (size_t)w * 64;
    for (int c4 = 0; c4 < 16; ++c4) {
        float v4[4];
        #pragma unroll
        for (int cq = 0; cq < 4; ++cq) {
            int c = c4 * 4 + cq;
            float acc = b1b[c];
            const float4* wr = (const float4*)(w1bT + (size_t)c * 64);
            #pragma unroll
            for (int q = 0; q < 16; ++q) {
                float4 wv = wr[q];
                acc = fmaf(h1[4 * q + 0], wv.x, acc);
                acc = fmaf(h1[4 * q + 1], wv.y, acc);
                acc = fmaf(h1[4 * q + 2], wv.z, acc);
                acc = fmaf(h1[4 * q + 3], wv.w, acc);
            }
            float v = fmaxf(acc, 0.0f);
            v = valid ? v : -__builtin_inff();
            #pragma unroll
            for (int o = 32; o > 0; o >>= 1) v = fmaxf(v, __shfl_xor(v, o, 64));
            v4[cq] = v;
        }
        if (lane == 0)
            ((float4*)orow)[c4] = make_float4(v4[0], v4[1], v4[2], v4[3]);
    }
}

// ---------------------------------------------------------------------------
// MLP2 (standalone, R13-proven): [x1(64)|relpos(3)] -> 128 relu -> 128 relu,
// masked max; writes x2 into X rows (cols 0..127).
// ---------------------------------------------------------------------------
__global__ __launch_bounds__(256)
void mlp2_kernel(const float* __restrict__ x1, const float* __restrict__ c1,
                 const float* __restrict__ c2, const int* __restrict__ nbr2,
                 const float* __restrict__ w2aT, const float* __restrict__ w2bT,
                 const float* __restrict__ b2b, float* __restrict__ X) {
    const int lane = threadIdx.x & 63;
    int w = __builtin_amdgcn_readfirstlane((int)(blockIdx.x * 4 + (threadIdx.x >> 6)));
    const int b = w >> 9;
    const int ii = nbr2[(size_t)w * Kn + lane];
    const bool valid = ii >= 0;
    const int i2 = valid ? ii : 0;

    float x[68];
    const float4* xr = (const float4*)(x1 + ((size_t)b * M1 + i2) * 64);
    #pragma unroll
    for (int q = 0; q < 16; ++q) {
        float4 v = xr[q];
        x[4 * q + 0] = v.x; x[4 * q + 1] = v.y;
        x[4 * q + 2] = v.z; x[4 * q + 3] = v.w;
    }
    const float* cc = c2 + (size_t)w * 3;
    const float* cp = c1 + ((size_t)b * M1 + i2) * 3;
    x[64] = cp[0] - cc[0];
    x[65] = cp[1] - cc[1];
    x[66] = cp[2] - cc[2];
    x[67] = 0.0f;

    float h1[128];
    #pragma unroll
    for (int h = 0; h < 128; ++h) {
        const float4* r4 = (const float4*)(w2aT + (size_t)h * 80);
        float acc = 0.0f;
        #pragma unroll
        for (int q = 0; q < 16; ++q) {
            float4 wv = r4[q];
            acc = fmaf(x[4 * q + 0], wv.x, acc);
            acc = fmaf(x[4 * q + 1], wv.y, acc);
            acc = fmaf(x[4 * q + 2], wv.z, acc);
            acc = fmaf(x[4 * q + 3], wv.w, acc);
        }
        float4 tl = r4[16];   // w64, w65, w66, bias
        acc = fmaf(x[64], tl.x, acc);
        acc = fmaf(x[65], tl.y, acc);
        acc = fmaf(x[66], tl.z, acc);
        acc += tl.w;
        h1[h] = fmaxf(acc, 0.0f);
    }
    float* orow = X + (size_t)w * LDX;
    for (int c4 = 0; c4 < 32; ++c4) {
        float v4[4];
        #pragma unroll
        for (int cq = 0; cq < 4; ++cq) {
            int c = c4 * 4 + cq;
            float acc = b2b[c];
            const float4* wr = (const float4*)(w2bT + (size_t)c * 128);
            #pragma unroll
            for (int q = 0; q < 32; ++q) {
                float4 wv = wr[q];
                acc = fmaf(h1[4 * q + 0], wv.x, acc);
                acc = fmaf(h1[4 * q + 1], wv.y, acc);
                acc = fmaf(h1[4 * q + 2], wv.z, acc);
                acc = fmaf(h1[4 * q + 3], wv.w, acc);
            }
            float v = fmaxf(acc, 0.0f);
            v = valid ? v : -__builtin_inff();
            #pragma unroll
            for (int o = 32; o > 0; o >>= 1) v = fmaxf(v, __shfl_xor(v, o, 64));
            v4[cq] = v;
        }
        if (lane == 0) {
            orow[c4 * 4 + 0] = v4[0]; orow[c4 * 4 + 1] = v4[1];
            orow[c4 * 4 + 2] = v4[2]; orow[c4 * 4 + 3] = v4[3];
        }
    }
}

// ---------------------------------------------------------------------------
// GEMM1: H[r][c] = relu(b3a[c] + sum_i X[r][i] * w3a[i][c]), K=131.
// ---------------------------------------------------------------------------
__global__ __launch_bounds__(256)
void gemm1_kernel(const float* __restrict__ X, const float* __restrict__ w3a,
                  const float* __restrict__ b3a, float* __restrict__ H) {
    const int r = blockIdx.x;
    const int c = threadIdx.x;
    const float* xr = X + (size_t)r * LDX;
    float acc = b3a[c];
    for (int i = 0; i < 131; ++i)
        acc = fmaf(xr[i], w3a[(size_t)i * 256 + c], acc);
    H[(size_t)r * 256 + c] = fmaxf(acc, 0.0f);
}

// ---------------------------------------------------------------------------
// GEMM2 fused with per-tile row max: 32x64 tile, BK=32.
// ---------------------------------------------------------------------------
__global__ __launch_bounds__(256)
void gemm2_kernel(const float* __restrict__ H, const float* __restrict__ w3b,
                  float* __restrict__ part) {
    __shared__ float As[32][33];
    __shared__ float Bs[32][64];
    __shared__ float red[8][64];
    const int bidx = blockIdx.x;
    const int nt = bidx & 15;
    const int mt = (bidx >> 4) & 15;
    const int b = bidx >> 8;
    const int row0 = b * M2 + mt * 32;
    const int col0 = nt * 64;
    const int t = threadIdx.x;
    const int rg = t >> 5, cg = t & 31;

    float acc[4][2] = {{0.f, 0.f}, {0.f, 0.f}, {0.f, 0.f}, {0.f, 0.f}};
    for (int k0 = 0; k0 < 256; k0 += 32) {
        #pragma unroll
        for (int q = 0; q < 4; ++q) {
            int id = t + q * 256;
            As[id >> 5][id & 31] = H[(size_t)(row0 + (id >> 5)) * 256 + k0 + (id & 31)];
        }
        #pragma unroll
        for (int q = 0; q < 8; ++q) {
            int id = t + q * 256;
            Bs[id >> 6][id & 63] = w3b[(size_t)(k0 + (id >> 6)) * 1024 + col0 + (id & 63)];
        }
        __syncthreads();
        #pragma unroll
        for (int kk = 0; kk < 32; ++kk) {
            float b0 = Bs[kk][cg * 2 + 0];
            float b1 = Bs[kk][cg * 2 + 1];
            #pragma unroll
            for (int j = 0; j < 4; ++j) {
                float a = As[rg * 4 + j][kk];
                acc[j][0] = fmaf(a, b0, acc[j][0]);
                acc[j][1] = fmaf(a, b1, acc[j][1]);
            }
        }
        __syncthreads();
    }
    float m0 = fmaxf(fmaxf(acc[0][0], acc[1][0]), fmaxf(acc[2][0], acc[3][0]));
    float m1 = fmaxf(fmaxf(acc[0][1], acc[1][1]), fmaxf(acc[2][1], acc[3][1]));
    red[rg][cg * 2 + 0] = m0;
    red[rg][cg * 2 + 1] = m1;
    __syncthreads();
    if (t < 64) {
        float v = red[0][t];
        #pragma unroll
        for (int q = 1; q < 8; ++q) v = fmaxf(v, red[q][t]);
        part[((size_t)b * 16 + mt) * 1024 + col0 + t] = v;
    }
}

// ---------------------------------------------------------------------------
// Final max over the 16 m-tiles per cloud + bias.
// ---------------------------------------------------------------------------
__global__ __launch_bounds__(256)
void rmax_kernel(const float* __restrict__ part, const float* __restrict__ b3b,
                 float* __restrict__ out) {
    int i = blockIdx.x * 256 + threadIdx.x;  // 8192 = B*1024
    int b = i >> 10, c = i & 1023;
    float v = -__builtin_inff();
    #pragma unroll
    for (int tt = 0; tt < 16; ++tt)
        v = fmaxf(v, part[((size_t)b * 16 + tt) * 1024 + c]);
    out[i] = v + b3b[c];
}

// ---------------------------------------------------------------------------
extern "C" void kernel_launch(void* const* d_in, const int* in_sizes, int n_in,
                              void* d_out, int out_size, void* d_ws, size_t ws_size,
                              hipStream_t stream) {
    const float* pos = (const float*)d_in[0];
    const float* w1a = (const float*)d_in[1];
    const float* b1a = (const float*)d_in[2];
    const float* w1b = (const float*)d_in[3];
    const float* b1b = (const float*)d_in[4];
    const float* w2a = (const float*)d_in[5];
    const float* b2a = (const float*)d_in[6];
    const float* w2b = (const float*)d_in[7];
    const float* b2b = (const float*)d_in[8];
    const float* w3a = (const float*)d_in[9];
    const float* b3a = (const float*)d_in[10];
    const float* w3b = (const float*)d_in[11];
    const float* b3b = (const float*)d_in[12];
    float* out = (float*)d_out;

    char* ws = (char*)d_ws;
    size_t off = 0;
    auto alloc = [&](size_t bytes) -> char* {
        char* p = ws + off;
        off += (bytes + 255) & ~(size_t)255;
        return p;
    };
    float*  c1     = (float*)alloc(sizeof(float) * Bc * M1 * 3);
    float*  c2     = (float*)alloc(sizeof(float) * Bc * M2 * 3);
    int*    nbr1   = (int*)alloc(sizeof(int) * Bc * M1 * Kn);
    int*    nbr2   = (int*)alloc(sizeof(int) * Bc * M2 * Kn);
    float*  x1     = (float*)alloc(sizeof(float) * Bc * M1 * 64);
    float*  X      = (float*)alloc(sizeof(float) * Bc * M2 * LDX);
    float*  H      = (float*)alloc(sizeof(float) * Bc * M2 * 256);
    float*  part   = (float*)alloc(sizeof(float) * Bc * 16 * 1024);
    float*  w1aT   = (float*)alloc(sizeof(float) * 64 * 4);
    float*  w1bT   = (float*)alloc(sizeof(float) * 64 * 64);
    float*  w2aT   = (float*)alloc(sizeof(float) * 128 * 80);
    float*  w2bT   = (float*)alloc(sizeof(float) * 128 * 128);
    float4* scp1_g = (float4*)alloc(sizeof(float4) * Bc * Np);
    float*  mind1g = (float*)alloc(sizeof(float) * Bc * Np);
    float4* scp2_g = (float4*)alloc(sizeof(float4) * Bc * M1);
    float*  mind2g = (float*)alloc(sizeof(float) * Bc * M1);

    auto launch = [&](int grid, int fs, int sb, int se, int wsg, int wbg, int wsh) {
        stage_kernel<<<dim3(grid), dim3(512), 0, stream>>>(
            fs, sb, se, wsg, wbg, wsh,
            pos, c1, c2, X, nbr1, nbr2, scp1_g, mind1g, scp2_g, mind2g,
            w1a, b1a, w1b, w2a, b2a, w2b, w1aT, w1bT, w2aT, w2bT);
    };

    // LA: fps1 chunk [0,512) + weight prep
    launch(Bc + 32, 1, 0, 512, 1, 0, 0);
    // LB1..3: fps1 chunks + bq1 workers for the previous chunk (span 512)
    launch(Bc + 240, 1, 512, 1024, 2, 0, 9);
    launch(Bc + 240, 1, 1024, 1536, 2, 512, 9);
    launch(Bc + 240, 1, 1536, 2048, 2, 1024, 9);
    // LC: fps2 chunk [0,256) + bq1 workers for fps1 chunk 3 (span 512)
    launch(Bc + 240, 2, 0, 256, 2, 1536, 9);
    // LD: fps2 chunk [256,512) + bq2 workers for fps2 chunk 0 (span 256)
    launch(Bc + 240, 2, 256, 512, 3, 0, 8);
    // LE: bq2 workers for fps2 chunk 1 (span 256)
    launch(240, 0, 0, 0, 3, 256, 8);

    mlp1_kernel<<<dim3(Bc * M1 / 4), dim3(256), 0, stream>>>(
        pos, c1, nbr1, w1aT, w1bT, b1b, x1);
    mlp2_kernel<<<dim3(Bc * M2 / 4), dim3(256), 0, stream>>>(
        x1, c1, c2, nbr2, w2aT, w2bT, b2b, X);
    gemm1_kernel<<<dim3(Bc * M2), dim3(256), 0, stream>>>(X, w3a, b3a, H);
    gemm2_kernel<<<dim3(Bc * 16 * 16), dim3(256), 0, stream>>>(H, w3b, part);
    rmax_kernel<<<dim3(32), dim3(256), 0, stream>>>(part, b3b, out);
}